// Round 1
// baseline (4663.707 us; speedup 1.0000x reference)
//
#include <hip/hip_runtime.h>
#include <cstdint>
#include <cstddef>

#define NN 50000
#define EE 800000
#define NNZ (NN + EE)
#define KK 20
#define TPK 30

// ---------------- preprocessing ----------------

__global__ __launch_bounds__(256) void init_deg(int* deg) {
  int t = blockIdx.x * 256 + threadIdx.x;
  if (t < NN) deg[t] = 1;  // self-loop
}

__global__ __launch_bounds__(256) void count_deg(const int* __restrict__ ecol, int* deg) {
  int t = blockIdx.x * 256 + threadIdx.x;
  if (t < EE) atomicAdd(&deg[ecol[t]], 1);
}

__global__ __launch_bounds__(1024) void scan_rowptr(const int* __restrict__ deg, int* rowptr,
                                                    int* cursor, float* dinv) {
  __shared__ int part[1024];
  int tid = threadIdx.x;
  const int CH = (NN + 1023) / 1024;  // 49
  int begin = tid * CH;
  int end = begin + CH; if (end > NN) end = NN;
  int sum = 0;
  for (int i = begin; i < end; ++i) sum += deg[i];
  part[tid] = sum;
  __syncthreads();
  for (int o = 1; o < 1024; o <<= 1) {
    int v = part[tid];
    int u = (tid >= o) ? part[tid - o] : 0;
    __syncthreads();
    part[tid] = v + u;
    __syncthreads();
  }
  int run = (tid > 0) ? part[tid - 1] : 0;  // exclusive prefix
  for (int i = begin; i < end; ++i) {
    rowptr[i] = run;
    cursor[i] = run;
    dinv[i] = 1.0f / sqrtf((float)deg[i]);
    run += deg[i];
  }
  if (tid == 1023) rowptr[NN] = part[1023];
}

__global__ __launch_bounds__(256) void scatter_csr(const int* __restrict__ erow,
                                                   const int* __restrict__ ecol,
                                                   const float* __restrict__ dinv, int* cursor,
                                                   int* __restrict__ csrc, float* __restrict__ cnrm) {
  int t = blockIdx.x * 256 + threadIdx.x;
  if (t < EE) {
    int r = erow[t], c = ecol[t];
    int p = atomicAdd(&cursor[c], 1);
    csrc[p] = r;
    cnrm[p] = dinv[r] * dinv[c];
  } else if (t < NNZ) {
    int i = t - EE;
    int p = atomicAdd(&cursor[i], 1);
    csrc[p] = i;
    cnrm[p] = dinv[i] * dinv[i];
  }
}

__global__ __launch_bounds__(256) void extract_x0(const float* __restrict__ x, float* __restrict__ x0) {
  int t = blockIdx.x * 256 + threadIdx.x;
  if (t < NN * 4) x0[t] = x[(t >> 2) * 8 + (t & 3)];
}

// ---------------- propagation sweeps ----------------
// tout[v] = aacc * sum_e nrm[e]*tin[src[e]] + ax * xin[v]

__global__ __launch_bounds__(256) void sweep4(const float* __restrict__ tin,
                                              const float* __restrict__ xin,
                                              float* __restrict__ tout,
                                              const int* __restrict__ rowptr,
                                              const int* __restrict__ src,
                                              const float* __restrict__ nrm,
                                              float aacc, float ax) {
  int t = blockIdx.x * 256 + threadIdx.x;
  if (t >= NN * 4) return;
  int v = t >> 2, c = t & 3;
  int s = rowptr[v], e = rowptr[v + 1];
  float acc = 0.f;
  for (int i = s; i < e; ++i)
    acc = fmaf(nrm[i], tin[(size_t)src[i] * 4 + c], acc);
  tout[t] = aacc * acc + ax * xin[t];
}

__global__ __launch_bounds__(256) void sweep64(const float* __restrict__ tin,
                                               const float* __restrict__ xin,
                                               float* __restrict__ tout,
                                               const int* __restrict__ rowptr,
                                               const int* __restrict__ src,
                                               const float* __restrict__ nrm,
                                               float aacc, float ax) {
  int lane = threadIdx.x & 63;
  int w = threadIdx.x >> 6;
  int v = blockIdx.x * 4 + w;
  if (v >= NN) return;
  int s = __builtin_amdgcn_readfirstlane(rowptr[v]);
  int e = __builtin_amdgcn_readfirstlane(rowptr[v + 1]);
  float acc0 = 0.f, acc1 = 0.f;
  int i = s;
  for (; i + 1 < e; i += 2) {
    int u0 = src[i], u1 = src[i + 1];
    float w0 = nrm[i], w1 = nrm[i + 1];
    acc0 = fmaf(w0, tin[(size_t)u0 * 64 + lane], acc0);
    acc1 = fmaf(w1, tin[(size_t)u1 * 64 + lane], acc1);
  }
  if (i < e)
    acc0 = fmaf(nrm[i], tin[(size_t)src[i] * 64 + lane], acc0);
  size_t o = (size_t)v * 64 + lane;
  tout[o] = aacc * (acc0 + acc1) + ax * xin[o];
}

// ---------------- dense layers ----------------

__global__ __launch_bounds__(256) void dense4(const float* __restrict__ h4,
                                              const float* __restrict__ W,  // [64][4]
                                              const float* __restrict__ b,
                                              float* __restrict__ out) {
  __shared__ float sWt[4 * 64];
  int tid = threadIdx.x;
  if (tid < 256) {
    int j = tid >> 2, c = tid & 3;
    sWt[c * 64 + j] = W[tid];
  }
  __syncthreads();
  int lane = tid & 63, w = tid >> 6;
  int n = blockIdx.x * 4 + w;
  if (n >= NN) return;
  float acc = b[lane];
#pragma unroll
  for (int c = 0; c < 4; ++c)
    acc = fmaf(h4[(size_t)n * 4 + c], sWt[c * 64 + lane], acc);
  acc = fmaxf(acc, 0.f);
  out[(size_t)n * 64 + lane] = acc;
}

__global__ __launch_bounds__(256) void dense64(const float* __restrict__ h,
                                               const float* __restrict__ W,  // [64][64]
                                               const float* __restrict__ b,
                                               const float* __restrict__ resid,
                                               float* __restrict__ out,
                                               int doRelu, int doResid) {
  __shared__ float sWt[64 * 64];
  int tid = threadIdx.x;
  for (int i = tid; i < 64 * 64; i += 256) {
    int j = i >> 6, c = i & 63;
    sWt[c * 64 + j] = W[i];
  }
  __syncthreads();
  int lane = tid & 63, w = tid >> 6;
  int n = blockIdx.x * 4 + w;
  if (n >= NN) return;
  float hv = h[(size_t)n * 64 + lane];
  float acc = b[lane];
#pragma unroll
  for (int c = 0; c < 64; ++c)
    acc = fmaf(__shfl(hv, c), sWt[c * 64 + lane], acc);
  if (doRelu) acc = fmaxf(acc, 0.f);
  if (doResid) acc += resid[(size_t)n * 64 + lane];
  out[(size_t)n * 64 + lane] = acc;
}

// ---------------- scoring / selection / output ----------------

__global__ void wp_norm(const float* __restrict__ wp, float* invn) {
  int lane = threadIdx.x;
  float v = wp[lane];
  float s = v * v;
#pragma unroll
  for (int o = 32; o > 0; o >>= 1) s += __shfl_xor(s, o);
  if (lane == 0) invn[0] = 1.0f / sqrtf(s);
}

__global__ __launch_bounds__(256) void score_k(const float* __restrict__ y,
                                               const float* __restrict__ wp,
                                               const float* __restrict__ invn,
                                               float* __restrict__ scores) {
  int tid = threadIdx.x;
  int lane = tid & 63, w = tid >> 6;
  int n = blockIdx.x * 4 + w;
  if (n >= NN) return;
  float p = y[(size_t)n * 64 + lane] * wp[lane];
#pragma unroll
  for (int o = 32; o > 0; o >>= 1) p += __shfl_xor(p, o);
  if (lane == 0) scores[n] = tanhf(p * invn[0]);
}

__device__ __forceinline__ bool lexgt(float v1, int i1, float v2, int i2) {
  return (v1 > v2) || (v1 == v2 && i1 < i2);
}

__global__ __launch_bounds__(256) void topk30(const float* __restrict__ score,
                                              int* __restrict__ sel_i, float* __restrict__ sel_v) {
  __shared__ float sv[256 * TPK];
  __shared__ int si[256 * TPK];
  __shared__ float rv[256];
  __shared__ int ri[256];
  int tid = threadIdx.x;
  float lv[TPK];
  int li[TPK];
#pragma unroll
  for (int k = 0; k < TPK; ++k) { lv[k] = -3.4e38f; li[k] = 0x7FFFFFFF; }
  for (int i = tid; i < NN; i += 256) {
    float v = score[i];
    if (lexgt(v, i, lv[TPK - 1], li[TPK - 1])) {
      float cv = v; int ci = i;
#pragma unroll
      for (int k = 0; k < TPK; ++k) {
        bool sw = lexgt(cv, ci, lv[k], li[k]);
        float tv = sw ? lv[k] : cv; int ti = sw ? li[k] : ci;
        lv[k] = sw ? cv : lv[k]; li[k] = sw ? ci : li[k];
        cv = tv; ci = ti;
      }
    }
  }
#pragma unroll
  for (int k = 0; k < TPK; ++k) { sv[tid * TPK + k] = lv[k]; si[tid * TPK + k] = li[k]; }
  __syncthreads();
  for (int r = 0; r < TPK; ++r) {
    float bv = -3.4e38f; int bi = 0x7FFFFFFF; int bp = -1;
#pragma unroll
    for (int k = 0; k < TPK; ++k) {
      float v = sv[tid * TPK + k]; int id = si[tid * TPK + k];
      if (lexgt(v, id, bv, bi)) { bv = v; bi = id; bp = tid * TPK + k; }
    }
    rv[tid] = bv; ri[tid] = bi;
    __syncthreads();
    if (tid < 64) {
      float v2 = rv[tid]; int i2 = ri[tid];
      for (int j = tid + 64; j < 256; j += 64)
        if (lexgt(rv[j], ri[j], v2, i2)) { v2 = rv[j]; i2 = ri[j]; }
#pragma unroll
      for (int o = 32; o > 0; o >>= 1) {
        float ov = __shfl_xor(v2, o); int oi = __shfl_xor(i2, o);
        if (lexgt(ov, oi, v2, i2)) { v2 = ov; i2 = oi; }
      }
      if (tid == 0) { rv[0] = v2; ri[0] = i2; sel_v[r] = v2; sel_i[r] = i2; }
    }
    __syncthreads();
    int wi = ri[0];
    if (bi == wi && bp >= 0) sv[bp] = -3.4e38f;
    __syncthreads();
  }
}

__global__ void final_max(const float* __restrict__ y, const int* __restrict__ sel_i,
                          const float* __restrict__ sel_v, float* __restrict__ out) {
  int c = threadIdx.x;  // 64 threads
  float m = -3.4e38f;
  for (int r = 0; r < TPK; ++r)
    m = fmaxf(m, y[(size_t)sel_i[r] * 64 + c] * sel_v[r]);
  out[c] = m;
}

// ---------------- host orchestration ----------------

extern "C" void kernel_launch(void* const* d_in, const int* in_sizes, int n_in,
                              void* d_out, int out_size, void* d_ws, size_t ws_size,
                              hipStream_t stream) {
  const float* x = (const float*)d_in[0];
  const int* ei = (const int*)d_in[1];
  const float* Wl[5] = {(const float*)d_in[2], (const float*)d_in[4], (const float*)d_in[6],
                        (const float*)d_in[8], (const float*)d_in[10]};
  const float* bl[5] = {(const float*)d_in[3], (const float*)d_in[5], (const float*)d_in[7],
                        (const float*)d_in[9], (const float*)d_in[11]};
  const float* Wm = (const float*)d_in[12];
  const float* bm = (const float*)d_in[13];
  const float* wp = (const float*)d_in[14];
  float* out = (float*)d_out;

  uint8_t* base = (uint8_t*)d_ws;
  size_t off = 0;
  auto alloc = [&](size_t bytes) -> void* {
    void* p = base + off;
    off += (bytes + 255) & ~(size_t)255;
    return p;
  };
  int* deg = (int*)alloc(NN * 4);
  int* rowptr = (int*)alloc((NN + 1) * 4);
  int* cursor = (int*)alloc(NN * 4);
  float* dinv = (float*)alloc(NN * 4);
  int* csrc = (int*)alloc((size_t)NNZ * 4);
  float* cnrm = (float*)alloc((size_t)NNZ * 4);
  float* x0 = (float*)alloc((size_t)NN * 4 * 4);
  float* t4a = (float*)alloc((size_t)NN * 4 * 4);
  float* t4b = (float*)alloc((size_t)NN * 4 * 4);
  float* xcur = (float*)alloc((size_t)NN * 64 * 4);
  float* tA = (float*)alloc((size_t)NN * 64 * 4);
  float* tB = (float*)alloc((size_t)NN * 64 * 4);
  float* scores = (float*)alloc(NN * 4);
  float* invn = (float*)alloc(256);
  int* seli = (int*)alloc(TPK * 4);
  float* selv = (float*)alloc(TPK * 4);

  const int* erow = ei;
  const int* ecol = ei + EE;

  init_deg<<<(NN + 255) / 256, 256, 0, stream>>>(deg);
  count_deg<<<(EE + 255) / 256, 256, 0, stream>>>(ecol, deg);
  scan_rowptr<<<1, 1024, 0, stream>>>(deg, rowptr, cursor, dinv);
  scatter_csr<<<(NNZ + 255) / 256, 256, 0, stream>>>(erow, ecol, dinv, cursor, csrc, cnrm);
  extract_x0<<<(NN * 4 + 255) / 256, 256, 0, stream>>>(x, x0);

  const float AL[5] = {0.7f, 0.7f, 0.35f, 0.7f / 3.0f, 0.175f};

  // layer 0 (cin = 4)
  {
    float coef = (1.0f - AL[0]) / (float)KK;
    const float* tin = x0;
    float* tout = t4a;
    for (int k = 1; k <= KK; ++k) {
      float aacc = (k == KK) ? coef : 1.0f;
      float ax = (k == KK) ? AL[0] : 1.0f;
      sweep4<<<(NN * 4 + 255) / 256, 256, 0, stream>>>(tin, x0, tout, rowptr, csrc, cnrm, aacc, ax);
      tin = tout;
      tout = (tout == t4a) ? t4b : t4a;
    }
    dense4<<<(NN + 3) / 4, 256, 0, stream>>>(tin, Wl[0], bl[0], xcur);
  }
  // layers 1..4 (cin = 64)
  for (int l = 1; l < 5; ++l) {
    float coef = (1.0f - AL[l]) / (float)KK;
    const float* tin = xcur;
    float* tout = tA;
    for (int k = 1; k <= KK; ++k) {
      float aacc = (k == KK) ? coef : 1.0f;
      float ax = (k == KK) ? AL[l] : 1.0f;
      sweep64<<<(NN + 3) / 4, 256, 0, stream>>>(tin, xcur, tout, rowptr, csrc, cnrm, aacc, ax);
      tin = tout;
      tout = (tout == tA) ? tB : tA;
    }
    dense64<<<(NN + 3) / 4, 256, 0, stream>>>(tin, Wl[l], bl[l], xcur, xcur, 1, (l >= 2) ? 1 : 0);
  }
  // final projection y = x @ Wm.T + bm  -> tA
  dense64<<<(NN + 3) / 4, 256, 0, stream>>>(xcur, Wm, bm, nullptr, tA, 0, 0);
  wp_norm<<<1, 64, 0, stream>>>(wp, invn);
  score_k<<<(NN + 3) / 4, 256, 0, stream>>>(tA, wp, invn, scores);
  topk30<<<1, 256, 0, stream>>>(scores, seli, selv);
  final_max<<<1, 64, 0, stream>>>(tA, seli, selv, out);
}

// Round 2
// 3471.816 us; speedup vs baseline: 1.3433x; 1.3433x over previous
//
#include <hip/hip_runtime.h>
#include <cstdint>
#include <cstddef>

#define NN 50000
#define EE 800000
#define NNZ (NN + EE)
#define KK 20
#define TPK 30
#define P1B 128
#define P1CH ((NN + P1B - 1) / P1B)  // 391

// ---------------- preprocessing ----------------

__global__ __launch_bounds__(256) void init_deg(int* deg) {
  int t = blockIdx.x * 256 + threadIdx.x;
  if (t < NN) deg[t] = 1;  // self-loop
}

__global__ __launch_bounds__(256) void count_deg(const int* __restrict__ ecol, int* deg) {
  int t = blockIdx.x * 256 + threadIdx.x;
  if (t < EE) atomicAdd(&deg[ecol[t]], 1);
}

__global__ __launch_bounds__(1024) void scan_rowptr(const int* __restrict__ deg, int* rowptr,
                                                    int* cursor, float* dinv) {
  __shared__ int part[1024];
  int tid = threadIdx.x;
  const int CH = (NN + 1023) / 1024;  // 49
  int begin = tid * CH;
  int end = begin + CH; if (end > NN) end = NN;
  int sum = 0;
  for (int i = begin; i < end; ++i) sum += deg[i];
  part[tid] = sum;
  __syncthreads();
  for (int o = 1; o < 1024; o <<= 1) {
    int v = part[tid];
    int u = (tid >= o) ? part[tid - o] : 0;
    __syncthreads();
    part[tid] = v + u;
    __syncthreads();
  }
  int run = (tid > 0) ? part[tid - 1] : 0;  // exclusive prefix
  for (int i = begin; i < end; ++i) {
    rowptr[i] = run;
    cursor[i] = run;
    dinv[i] = 1.0f / sqrtf((float)deg[i]);
    run += deg[i];
  }
  if (tid == 1023) rowptr[NN] = part[1023];
}

__global__ __launch_bounds__(256) void scatter_csr(const int* __restrict__ erow,
                                                   const int* __restrict__ ecol,
                                                   const float* __restrict__ dinv, int* cursor,
                                                   int* __restrict__ csrc, float* __restrict__ cnrm) {
  int t = blockIdx.x * 256 + threadIdx.x;
  if (t < EE) {
    int r = erow[t], c = ecol[t];
    int p = atomicAdd(&cursor[c], 1);
    csrc[p] = r;
    cnrm[p] = dinv[r] * dinv[c];
  } else if (t < NNZ) {
    int i = t - EE;
    int p = atomicAdd(&cursor[i], 1);
    csrc[p] = i;
    cnrm[p] = dinv[i] * dinv[i];
  }
}

__global__ __launch_bounds__(256) void extract_x0(const float* __restrict__ x, float4* __restrict__ x0) {
  int t = blockIdx.x * 256 + threadIdx.x;
  if (t < NN) x0[t] = *(const float4*)&x[(size_t)t * 8];
}

// ---------------- propagation sweeps ----------------
// tout[v] = aacc * sum_e nrm[e]*tin[src[e]] + axc * xin[v]

// 64-channel: one wave per node; lane = (edge_slot e4, float4 channel group c16).
__global__ __launch_bounds__(256) void sweep64(const float4* __restrict__ tin,
                                               const float4* __restrict__ xin,
                                               float4* __restrict__ tout,
                                               const int* __restrict__ rowptr,
                                               const int* __restrict__ src,
                                               const float* __restrict__ nrm,
                                               float aacc, float axc) {
  int lane = threadIdx.x & 63;
  int w = threadIdx.x >> 6;
  int v = blockIdx.x * 4 + w;
  if (v >= NN) return;  // whole wave exits together
  int c16 = lane & 15;
  int e4 = lane >> 4;
  int s = rowptr[v], e = rowptr[v + 1];
  float a0 = 0.f, a1 = 0.f, a2 = 0.f, a3 = 0.f;
  for (int i = s + e4; i < e; i += 4) {
    float wgt = nrm[i];
    float4 t = tin[(size_t)src[i] * 16 + c16];
    a0 = fmaf(wgt, t.x, a0);
    a1 = fmaf(wgt, t.y, a1);
    a2 = fmaf(wgt, t.z, a2);
    a3 = fmaf(wgt, t.w, a3);
  }
  a0 += __shfl_xor(a0, 16); a1 += __shfl_xor(a1, 16);
  a2 += __shfl_xor(a2, 16); a3 += __shfl_xor(a3, 16);
  a0 += __shfl_xor(a0, 32); a1 += __shfl_xor(a1, 32);
  a2 += __shfl_xor(a2, 32); a3 += __shfl_xor(a3, 32);
  if (e4 == 0) {
    float4 xv = xin[(size_t)v * 16 + c16];
    float4 o;
    o.x = aacc * a0 + axc * xv.x;
    o.y = aacc * a1 + axc * xv.y;
    o.z = aacc * a2 + axc * xv.z;
    o.w = aacc * a3 + axc * xv.w;
    tout[(size_t)v * 16 + c16] = o;
  }
}

// 4-channel: wave = 16 nodes x 4 edge slots; one float4 row per edge.
__global__ __launch_bounds__(256) void sweep4(const float4* __restrict__ tin,
                                              const float4* __restrict__ xin,
                                              float4* __restrict__ tout,
                                              const int* __restrict__ rowptr,
                                              const int* __restrict__ src,
                                              const float* __restrict__ nrm,
                                              float aacc, float axc) {
  int lane = threadIdx.x & 63;
  int w = threadIdx.x >> 6;
  int n16 = lane & 15;
  int e4 = lane >> 4;
  int v = (blockIdx.x * 4 + w) * 16 + n16;
  int vv = (v < NN) ? v : (NN - 1);
  int s = rowptr[vv], e = rowptr[vv + 1];
  float a0 = 0.f, a1 = 0.f, a2 = 0.f, a3 = 0.f;
  for (int i = s + e4; i < e; i += 4) {
    float wgt = nrm[i];
    float4 t = tin[src[i]];
    a0 = fmaf(wgt, t.x, a0);
    a1 = fmaf(wgt, t.y, a1);
    a2 = fmaf(wgt, t.z, a2);
    a3 = fmaf(wgt, t.w, a3);
  }
  a0 += __shfl_xor(a0, 16); a1 += __shfl_xor(a1, 16);
  a2 += __shfl_xor(a2, 16); a3 += __shfl_xor(a3, 16);
  a0 += __shfl_xor(a0, 32); a1 += __shfl_xor(a1, 32);
  a2 += __shfl_xor(a2, 32); a3 += __shfl_xor(a3, 32);
  if (e4 == 0 && v < NN) {
    float4 xv = xin[v];
    float4 o;
    o.x = aacc * a0 + axc * xv.x;
    o.y = aacc * a1 + axc * xv.y;
    o.z = aacc * a2 + axc * xv.z;
    o.w = aacc * a3 + axc * xv.w;
    tout[v] = o;
  }
}

// ---------------- dense layers ----------------

__global__ __launch_bounds__(256) void dense4(const float* __restrict__ h4,
                                              const float* __restrict__ W,  // [64][4]
                                              const float* __restrict__ b,
                                              float* __restrict__ out) {
  __shared__ float sWt[4 * 64];
  int tid = threadIdx.x;
  {
    int j = tid >> 2, c = tid & 3;
    sWt[c * 64 + j] = W[tid];
  }
  __syncthreads();
  int lane = tid & 63, w = tid >> 6;
  int n = blockIdx.x * 4 + w;
  if (n >= NN) return;
  float acc = b[lane];
#pragma unroll
  for (int c = 0; c < 4; ++c)
    acc = fmaf(h4[(size_t)n * 4 + c], sWt[c * 64 + lane], acc);
  acc = fmaxf(acc, 0.f);
  out[(size_t)n * 64 + lane] = acc;
}

// 128 nodes per block; thread = (node j, out-quarter q) covering nodes {j, j+64}, outs [16q,16q+16)
#define DN 128
__global__ __launch_bounds__(256) void dense64(const float* __restrict__ h,
                                               const float* __restrict__ W,  // [64][64]
                                               const float* __restrict__ b,
                                               const float* __restrict__ resid,
                                               float* __restrict__ out,
                                               int doRelu, int doResid) {
  __shared__ float sX[64 * 130];   // [c][node], stride 130 -> 2-way (free)
  __shared__ float sWt[64 * 68];   // [c][out], stride 68 -> b128-aligned rows
  int tid = threadIdx.x;
  int base = blockIdx.x * DN;
  for (int i = tid; i < 64 * 64; i += 256) {
    int o = i >> 6, c = i & 63;
    sWt[c * 68 + o] = W[i];
  }
  for (int i = tid; i < DN * 64; i += 256) {
    int node = i >> 6, c = i & 63;
    int n = base + node;
    sX[c * 130 + node] = (n < NN) ? h[(size_t)n * 64 + c] : 0.f;
  }
  __syncthreads();
  int j = tid & 63;
  int q = tid >> 6;
  float acc0[16], acc1[16];
#pragma unroll
  for (int o = 0; o < 16; ++o) { acc0[o] = b[q * 16 + o]; acc1[o] = acc0[o]; }
  for (int c = 0; c < 64; ++c) {
    float x0 = sX[c * 130 + j];
    float x1 = sX[c * 130 + 64 + j];
#pragma unroll
    for (int o4 = 0; o4 < 4; ++o4) {
      float4 wv = *(const float4*)&sWt[c * 68 + q * 16 + o4 * 4];
      acc0[o4 * 4 + 0] = fmaf(x0, wv.x, acc0[o4 * 4 + 0]);
      acc0[o4 * 4 + 1] = fmaf(x0, wv.y, acc0[o4 * 4 + 1]);
      acc0[o4 * 4 + 2] = fmaf(x0, wv.z, acc0[o4 * 4 + 2]);
      acc0[o4 * 4 + 3] = fmaf(x0, wv.w, acc0[o4 * 4 + 3]);
      acc1[o4 * 4 + 0] = fmaf(x1, wv.x, acc1[o4 * 4 + 0]);
      acc1[o4 * 4 + 1] = fmaf(x1, wv.y, acc1[o4 * 4 + 1]);
      acc1[o4 * 4 + 2] = fmaf(x1, wv.z, acc1[o4 * 4 + 2]);
      acc1[o4 * 4 + 3] = fmaf(x1, wv.w, acc1[o4 * 4 + 3]);
    }
  }
  int n0 = base + j, n1 = base + 64 + j;
#pragma unroll
  for (int half = 0; half < 2; ++half) {
    int n = half ? n1 : n0;
    float* acc = half ? acc1 : acc0;
    if (n < NN) {
#pragma unroll
      for (int o4 = 0; o4 < 4; ++o4) {
        float4 r;
        r.x = acc[o4 * 4 + 0]; r.y = acc[o4 * 4 + 1];
        r.z = acc[o4 * 4 + 2]; r.w = acc[o4 * 4 + 3];
        if (doRelu) {
          r.x = fmaxf(r.x, 0.f); r.y = fmaxf(r.y, 0.f);
          r.z = fmaxf(r.z, 0.f); r.w = fmaxf(r.w, 0.f);
        }
        if (doResid) {
          float4 rv = *(const float4*)&resid[(size_t)n * 64 + q * 16 + o4 * 4];
          r.x += rv.x; r.y += rv.y; r.z += rv.z; r.w += rv.w;
        }
        *(float4*)&out[(size_t)n * 64 + q * 16 + o4 * 4] = r;
      }
    }
  }
}

// ---------------- scoring / selection / output ----------------

__global__ void wp_norm(const float* __restrict__ wp, float* invn) {
  int lane = threadIdx.x;
  float v = wp[lane];
  float s = v * v;
#pragma unroll
  for (int o = 32; o > 0; o >>= 1) s += __shfl_xor(s, o);
  if (lane == 0) invn[0] = 1.0f / sqrtf(s);
}

__global__ __launch_bounds__(256) void score_k(const float* __restrict__ y,
                                               const float* __restrict__ wp,
                                               const float* __restrict__ invn,
                                               float* __restrict__ scores) {
  int tid = threadIdx.x;
  int lane = tid & 63, w = tid >> 6;
  int n = blockIdx.x * 4 + w;
  if (n >= NN) return;
  float p = y[(size_t)n * 64 + lane] * wp[lane];
#pragma unroll
  for (int o = 32; o > 0; o >>= 1) p += __shfl_xor(p, o);
  if (lane == 0) scores[n] = tanhf(p * invn[0]);
}

__device__ __forceinline__ bool lexgt(float v1, int i1, float v2, int i2) {
  return (v1 > v2) || (v1 == v2 && i1 < i2);
}

// phase 1: each of P1B blocks emits its local top-30 (argmax-and-remove in LDS)
__global__ __launch_bounds__(256) void topk_p1(const float* __restrict__ score,
                                               float* __restrict__ candv, int* __restrict__ candi) {
  __shared__ float sv[P1CH];
  __shared__ int si[P1CH];
  __shared__ float wvv[4];
  __shared__ int wii[4];
  __shared__ int wpp[4];
  int tid = threadIdx.x;
  int base = blockIdx.x * P1CH;
  for (int k = tid; k < P1CH; k += 256) {
    int idx = base + k;
    bool ok = idx < NN;
    sv[k] = ok ? score[idx] : -3.4e38f;
    si[k] = ok ? idx : 0x7FFFFFFF;
  }
  __syncthreads();
  for (int r = 0; r < TPK; ++r) {
    float bv = -3.4e38f; int bi = 0x7FFFFFFF; int bp = -1;
    for (int k = tid; k < P1CH; k += 256) {
      if (lexgt(sv[k], si[k], bv, bi)) { bv = sv[k]; bi = si[k]; bp = k; }
    }
#pragma unroll
    for (int o = 32; o > 0; o >>= 1) {
      float ov = __shfl_xor(bv, o); int oi = __shfl_xor(bi, o); int op = __shfl_xor(bp, o);
      if (lexgt(ov, oi, bv, bi)) { bv = ov; bi = oi; bp = op; }
    }
    if ((tid & 63) == 0) { int wl = tid >> 6; wvv[wl] = bv; wii[wl] = bi; wpp[wl] = bp; }
    __syncthreads();
    if (tid == 0) {
      float fv = wvv[0]; int fi = wii[0]; int fp = wpp[0];
#pragma unroll
      for (int u = 1; u < 4; ++u)
        if (lexgt(wvv[u], wii[u], fv, fi)) { fv = wvv[u]; fi = wii[u]; fp = wpp[u]; }
      candv[blockIdx.x * TPK + r] = fv;
      candi[blockIdx.x * TPK + r] = fi;
      if (fp >= 0) { sv[fp] = -3.4e38f; si[fp] = 0x7FFFFFFF; }
    }
    __syncthreads();
  }
}

// phase 2: merge P1B*30 candidates into the global top-30
__global__ __launch_bounds__(256) void topk_p2(const float* __restrict__ candv,
                                               const int* __restrict__ candi,
                                               int* __restrict__ sel_i, float* __restrict__ sel_v) {
  __shared__ float sv[P1B * TPK];
  __shared__ int si[P1B * TPK];
  __shared__ float wvv[4];
  __shared__ int wii[4];
  __shared__ int wpp[4];
  int tid = threadIdx.x;
  for (int k = tid; k < P1B * TPK; k += 256) { sv[k] = candv[k]; si[k] = candi[k]; }
  __syncthreads();
  for (int r = 0; r < TPK; ++r) {
    float bv = -3.4e38f; int bi = 0x7FFFFFFF; int bp = -1;
    for (int k = tid; k < P1B * TPK; k += 256) {
      if (lexgt(sv[k], si[k], bv, bi)) { bv = sv[k]; bi = si[k]; bp = k; }
    }
#pragma unroll
    for (int o = 32; o > 0; o >>= 1) {
      float ov = __shfl_xor(bv, o); int oi = __shfl_xor(bi, o); int op = __shfl_xor(bp, o);
      if (lexgt(ov, oi, bv, bi)) { bv = ov; bi = oi; bp = op; }
    }
    if ((tid & 63) == 0) { int wl = tid >> 6; wvv[wl] = bv; wii[wl] = bi; wpp[wl] = bp; }
    __syncthreads();
    if (tid == 0) {
      float fv = wvv[0]; int fi = wii[0]; int fp = wpp[0];
#pragma unroll
      for (int u = 1; u < 4; ++u)
        if (lexgt(wvv[u], wii[u], fv, fi)) { fv = wvv[u]; fi = wii[u]; fp = wpp[u]; }
      sel_v[r] = fv;
      sel_i[r] = fi;
      if (fp >= 0) { sv[fp] = -3.4e38f; si[fp] = 0x7FFFFFFF; }
    }
    __syncthreads();
  }
}

__global__ void final_max(const float* __restrict__ y, const int* __restrict__ sel_i,
                          const float* __restrict__ sel_v, float* __restrict__ out) {
  int c = threadIdx.x;  // 64 threads
  float m = -3.4e38f;
  for (int r = 0; r < TPK; ++r)
    m = fmaxf(m, y[(size_t)sel_i[r] * 64 + c] * sel_v[r]);
  out[c] = m;
}

// ---------------- host orchestration ----------------

extern "C" void kernel_launch(void* const* d_in, const int* in_sizes, int n_in,
                              void* d_out, int out_size, void* d_ws, size_t ws_size,
                              hipStream_t stream) {
  const float* x = (const float*)d_in[0];
  const int* ei = (const int*)d_in[1];
  const float* Wl[5] = {(const float*)d_in[2], (const float*)d_in[4], (const float*)d_in[6],
                        (const float*)d_in[8], (const float*)d_in[10]};
  const float* bl[5] = {(const float*)d_in[3], (const float*)d_in[5], (const float*)d_in[7],
                        (const float*)d_in[9], (const float*)d_in[11]};
  const float* Wm = (const float*)d_in[12];
  const float* bm = (const float*)d_in[13];
  const float* wp = (const float*)d_in[14];
  float* out = (float*)d_out;

  uint8_t* base = (uint8_t*)d_ws;
  size_t off = 0;
  auto alloc = [&](size_t bytes) -> void* {
    void* p = base + off;
    off += (bytes + 255) & ~(size_t)255;
    return p;
  };
  int* deg = (int*)alloc(NN * 4);
  int* rowptr = (int*)alloc((NN + 1) * 4);
  int* cursor = (int*)alloc(NN * 4);
  float* dinv = (float*)alloc(NN * 4);
  int* csrc = (int*)alloc((size_t)NNZ * 4);
  float* cnrm = (float*)alloc((size_t)NNZ * 4);
  float* x0 = (float*)alloc((size_t)NN * 4 * 4);
  float* t4a = (float*)alloc((size_t)NN * 4 * 4);
  float* t4b = (float*)alloc((size_t)NN * 4 * 4);
  float* xcur = (float*)alloc((size_t)NN * 64 * 4);
  float* tA = (float*)alloc((size_t)NN * 64 * 4);
  float* tB = (float*)alloc((size_t)NN * 64 * 4);
  float* scores = (float*)alloc(NN * 4);
  float* invn = (float*)alloc(256);
  int* seli = (int*)alloc(TPK * 4);
  float* selv = (float*)alloc(TPK * 4);
  float* candv = (float*)alloc((size_t)P1B * TPK * 4);
  int* candi = (int*)alloc((size_t)P1B * TPK * 4);

  const int* erow = ei;
  const int* ecol = ei + EE;

  init_deg<<<(NN + 255) / 256, 256, 0, stream>>>(deg);
  count_deg<<<(EE + 255) / 256, 256, 0, stream>>>(ecol, deg);
  scan_rowptr<<<1, 1024, 0, stream>>>(deg, rowptr, cursor, dinv);
  scatter_csr<<<(NNZ + 255) / 256, 256, 0, stream>>>(erow, ecol, dinv, cursor, csrc, cnrm);
  extract_x0<<<(NN + 255) / 256, 256, 0, stream>>>(x, (float4*)x0);

  const float AL[5] = {0.7f, 0.7f, 0.35f, 0.7f / 3.0f, 0.175f};

  // layer 0 (cin = 4)
  {
    float coef = (1.0f - AL[0]) / (float)KK;
    const float* tin = x0;
    float* tout = t4a;
    for (int k = 1; k <= KK; ++k) {
      float aacc = (k == KK) ? coef : 1.0f;
      float axc = (k == KK) ? AL[0] : 1.0f;
      sweep4<<<(NN + 63) / 64, 256, 0, stream>>>((const float4*)tin, (const float4*)x0,
                                                 (float4*)tout, rowptr, csrc, cnrm, aacc, axc);
      tin = tout;
      tout = (tout == t4a) ? t4b : t4a;
    }
    dense4<<<(NN + 3) / 4, 256, 0, stream>>>(tin, Wl[0], bl[0], xcur);
  }
  // layers 1..4 (cin = 64)
  for (int l = 1; l < 5; ++l) {
    float coef = (1.0f - AL[l]) / (float)KK;
    const float* tin = xcur;
    float* tout = tA;
    for (int k = 1; k <= KK; ++k) {
      float aacc = (k == KK) ? coef : 1.0f;
      float axc = (k == KK) ? AL[l] : 1.0f;
      sweep64<<<(NN + 3) / 4, 256, 0, stream>>>((const float4*)tin, (const float4*)xcur,
                                                (float4*)tout, rowptr, csrc, cnrm, aacc, axc);
      tin = tout;
      tout = (tout == tA) ? tB : tA;
    }
    dense64<<<(NN + DN - 1) / DN, 256, 0, stream>>>(tin, Wl[l], bl[l], xcur, xcur, 1,
                                                    (l >= 2) ? 1 : 0);
  }
  // final projection y = x @ Wm.T + bm  -> tA
  dense64<<<(NN + DN - 1) / DN, 256, 0, stream>>>(xcur, Wm, bm, nullptr, tA, 0, 0);
  wp_norm<<<1, 64, 0, stream>>>(wp, invn);
  score_k<<<(NN + 3) / 4, 256, 0, stream>>>(tA, wp, invn, scores);
  topk_p1<<<P1B, 256, 0, stream>>>(scores, candv, candi);
  topk_p2<<<1, 256, 0, stream>>>(candv, candi, seli, selv);
  final_max<<<1, 64, 0, stream>>>(tA, seli, selv, out);
}

// Round 3
// 3064.065 us; speedup vs baseline: 1.5221x; 1.1331x over previous
//
#include <hip/hip_runtime.h>
#include <cstdint>
#include <cstddef>

#define NN 50000
#define EE 800000
#define NNZ (NN + EE)
#define KK 20
#define TPK 30
#define P1B 128
#define P1CH ((NN + P1B - 1) / P1B)  // 391
#define SCB 256
#define SCNB ((NN + SCB - 1) / SCB)  // 196

// ---------------- preprocessing ----------------

__global__ __launch_bounds__(256) void init_deg(int* deg) {
  int t = blockIdx.x * 256 + threadIdx.x;
  if (t < NN) deg[t] = 1;  // self-loop
}

__global__ __launch_bounds__(256) void count_deg(const int* __restrict__ ecol, int* deg) {
  int t = blockIdx.x * 256 + threadIdx.x;
  if (t < EE) atomicAdd(&deg[ecol[t]], 1);
}

__global__ __launch_bounds__(256) void scan_bsum(const int* __restrict__ deg, int* __restrict__ bsum) {
  __shared__ int red[256];
  int tid = threadIdx.x;
  int t = blockIdx.x * 256 + tid;
  red[tid] = (t < NN) ? deg[t] : 0;
  __syncthreads();
  for (int o = 128; o > 0; o >>= 1) {
    if (tid < o) red[tid] += red[tid + o];
    __syncthreads();
  }
  if (tid == 0) bsum[blockIdx.x] = red[0];
}

__global__ __launch_bounds__(256) void scan_boff(const int* __restrict__ bsum, int* __restrict__ boff) {
  __shared__ int s[256];
  int tid = threadIdx.x;
  int own = (tid < SCNB) ? bsum[tid] : 0;
  s[tid] = own;
  __syncthreads();
  for (int o = 1; o < 256; o <<= 1) {
    int v = s[tid];
    int u = (tid >= o) ? s[tid - o] : 0;
    __syncthreads();
    s[tid] = v + u;
    __syncthreads();
  }
  if (tid < SCNB) boff[tid] = s[tid] - own;  // exclusive
}

__global__ __launch_bounds__(256) void scan_write(const int* __restrict__ deg,
                                                  const int* __restrict__ boff,
                                                  int* __restrict__ rowptr, int* __restrict__ cursor,
                                                  float* __restrict__ dinv) {
  __shared__ int s[256];
  int tid = threadIdx.x;
  int t = blockIdx.x * 256 + tid;
  int d = (t < NN) ? deg[t] : 0;
  s[tid] = d;
  __syncthreads();
  for (int o = 1; o < 256; o <<= 1) {
    int v = s[tid];
    int u = (tid >= o) ? s[tid - o] : 0;
    __syncthreads();
    s[tid] = v + u;
    __syncthreads();
  }
  if (t < NN) {
    int excl = boff[blockIdx.x] + s[tid] - d;
    rowptr[t] = excl;
    cursor[t] = excl;
    dinv[t] = 1.0f / sqrtf((float)d);
    if (t == NN - 1) rowptr[NN] = excl + d;
  }
}

__global__ __launch_bounds__(256) void scatter_csr(const int* __restrict__ erow,
                                                   const int* __restrict__ ecol,
                                                   const float* __restrict__ dinv, int* cursor,
                                                   int2* __restrict__ meta) {
  int t = blockIdx.x * 256 + threadIdx.x;
  if (t < EE) {
    int r = erow[t], c = ecol[t];
    int p = atomicAdd(&cursor[c], 1);
    meta[p] = make_int2(r, __float_as_int(dinv[r] * dinv[c]));
  } else if (t < NNZ) {
    int i = t - EE;
    int p = atomicAdd(&cursor[i], 1);
    meta[p] = make_int2(i, __float_as_int(dinv[i] * dinv[i]));
  }
}

__global__ __launch_bounds__(256) void extract_x0(const float* __restrict__ x, float4* __restrict__ x0) {
  int t = blockIdx.x * 256 + threadIdx.x;
  if (t < NN) x0[t] = *(const float4*)&x[(size_t)t * 8];
}

// ---------------- propagation sweeps ----------------
// tout[v] = aacc * sum_e nrm[e]*tin[src[e]] + axc * xin[v]

// 64-channel: one wave per node; lane = (edge_slot e4, float4-channel c16).
// Edge loop unrolled x2 -> 8 independent gathers in flight per wave.
__global__ __launch_bounds__(256) void sweep64(const float4* __restrict__ tin,
                                               const float4* __restrict__ xin,
                                               float4* __restrict__ tout,
                                               const int* __restrict__ rowptr,
                                               const int2* __restrict__ meta,
                                               float aacc, float axc) {
  int lane = threadIdx.x & 63;
  int w = threadIdx.x >> 6;
  int v = blockIdx.x * 4 + w;
  if (v >= NN) return;  // whole wave exits together
  int c16 = lane & 15;
  int e4 = lane >> 4;
  int s = rowptr[v], e = rowptr[v + 1];
  float a0 = 0.f, a1 = 0.f, a2 = 0.f, a3 = 0.f;
  float b0 = 0.f, b1 = 0.f, b2 = 0.f, b3 = 0.f;
  int i = s + e4;
  for (; i + 4 < e; i += 8) {
    int2 m0 = meta[i];
    int2 m1 = meta[i + 4];
    float w0 = __int_as_float(m0.y);
    float w1 = __int_as_float(m1.y);
    float4 t0 = tin[(size_t)m0.x * 16 + c16];
    float4 t1 = tin[(size_t)m1.x * 16 + c16];
    a0 = fmaf(w0, t0.x, a0); a1 = fmaf(w0, t0.y, a1);
    a2 = fmaf(w0, t0.z, a2); a3 = fmaf(w0, t0.w, a3);
    b0 = fmaf(w1, t1.x, b0); b1 = fmaf(w1, t1.y, b1);
    b2 = fmaf(w1, t1.z, b2); b3 = fmaf(w1, t1.w, b3);
  }
  if (i < e) {
    int2 m0 = meta[i];
    float w0 = __int_as_float(m0.y);
    float4 t0 = tin[(size_t)m0.x * 16 + c16];
    a0 = fmaf(w0, t0.x, a0); a1 = fmaf(w0, t0.y, a1);
    a2 = fmaf(w0, t0.z, a2); a3 = fmaf(w0, t0.w, a3);
  }
  a0 += b0; a1 += b1; a2 += b2; a3 += b3;
  a0 += __shfl_xor(a0, 16); a1 += __shfl_xor(a1, 16);
  a2 += __shfl_xor(a2, 16); a3 += __shfl_xor(a3, 16);
  a0 += __shfl_xor(a0, 32); a1 += __shfl_xor(a1, 32);
  a2 += __shfl_xor(a2, 32); a3 += __shfl_xor(a3, 32);
  if (e4 == 0) {
    float4 xv = xin[(size_t)v * 16 + c16];
    float4 o;
    o.x = aacc * a0 + axc * xv.x;
    o.y = aacc * a1 + axc * xv.y;
    o.z = aacc * a2 + axc * xv.z;
    o.w = aacc * a3 + axc * xv.w;
    tout[(size_t)v * 16 + c16] = o;
  }
}

// 4-channel: wave = 16 nodes x 4 edge slots; one float4 row per edge; unrolled x2.
__global__ __launch_bounds__(256) void sweep4(const float4* __restrict__ tin,
                                              const float4* __restrict__ xin,
                                              float4* __restrict__ tout,
                                              const int* __restrict__ rowptr,
                                              const int2* __restrict__ meta,
                                              float aacc, float axc) {
  int lane = threadIdx.x & 63;
  int w = threadIdx.x >> 6;
  int n16 = lane & 15;
  int e4 = lane >> 4;
  int v = (blockIdx.x * 4 + w) * 16 + n16;
  int vv = (v < NN) ? v : (NN - 1);
  int s = rowptr[vv], e = rowptr[vv + 1];
  float a0 = 0.f, a1 = 0.f, a2 = 0.f, a3 = 0.f;
  float b0 = 0.f, b1 = 0.f, b2 = 0.f, b3 = 0.f;
  int i = s + e4;
  for (; i + 4 < e; i += 8) {
    int2 m0 = meta[i];
    int2 m1 = meta[i + 4];
    float w0 = __int_as_float(m0.y);
    float w1 = __int_as_float(m1.y);
    float4 t0 = tin[m0.x];
    float4 t1 = tin[m1.x];
    a0 = fmaf(w0, t0.x, a0); a1 = fmaf(w0, t0.y, a1);
    a2 = fmaf(w0, t0.z, a2); a3 = fmaf(w0, t0.w, a3);
    b0 = fmaf(w1, t1.x, b0); b1 = fmaf(w1, t1.y, b1);
    b2 = fmaf(w1, t1.z, b2); b3 = fmaf(w1, t1.w, b3);
  }
  if (i < e) {
    int2 m0 = meta[i];
    float w0 = __int_as_float(m0.y);
    float4 t0 = tin[m0.x];
    a0 = fmaf(w0, t0.x, a0); a1 = fmaf(w0, t0.y, a1);
    a2 = fmaf(w0, t0.z, a2); a3 = fmaf(w0, t0.w, a3);
  }
  a0 += b0; a1 += b1; a2 += b2; a3 += b3;
  a0 += __shfl_xor(a0, 16); a1 += __shfl_xor(a1, 16);
  a2 += __shfl_xor(a2, 16); a3 += __shfl_xor(a3, 16);
  a0 += __shfl_xor(a0, 32); a1 += __shfl_xor(a1, 32);
  a2 += __shfl_xor(a2, 32); a3 += __shfl_xor(a3, 32);
  if (e4 == 0 && v < NN) {
    float4 xv = xin[v];
    float4 o;
    o.x = aacc * a0 + axc * xv.x;
    o.y = aacc * a1 + axc * xv.y;
    o.z = aacc * a2 + axc * xv.z;
    o.w = aacc * a3 + axc * xv.w;
    tout[v] = o;
  }
}

// ---------------- dense layers ----------------

__global__ __launch_bounds__(256) void dense4(const float* __restrict__ h4,
                                              const float* __restrict__ W,  // [64][4]
                                              const float* __restrict__ b,
                                              float* __restrict__ out) {
  __shared__ float sWt[4 * 64];
  int tid = threadIdx.x;
  {
    int j = tid >> 2, c = tid & 3;
    sWt[c * 64 + j] = W[tid];
  }
  __syncthreads();
  int lane = tid & 63, w = tid >> 6;
  int n = blockIdx.x * 4 + w;
  if (n >= NN) return;
  float acc = b[lane];
#pragma unroll
  for (int c = 0; c < 4; ++c)
    acc = fmaf(h4[(size_t)n * 4 + c], sWt[c * 64 + lane], acc);
  acc = fmaxf(acc, 0.f);
  out[(size_t)n * 64 + lane] = acc;
}

// 128 nodes per block; thread = (node j, out-quarter q) covering nodes {j, j+64}, outs [16q,16q+16)
#define DN 128
__global__ __launch_bounds__(256) void dense64(const float* __restrict__ h,
                                               const float* __restrict__ W,  // [64][64]
                                               const float* __restrict__ b,
                                               const float* __restrict__ resid,
                                               float* __restrict__ out,
                                               int doRelu, int doResid) {
  __shared__ float sX[64 * 130];   // [c][node], stride 130 -> 2-way (free)
  __shared__ float sWt[64 * 68];   // [c][out], stride 68 -> b128-aligned rows
  int tid = threadIdx.x;
  int base = blockIdx.x * DN;
  for (int i = tid; i < 64 * 64; i += 256) {
    int o = i >> 6, c = i & 63;
    sWt[c * 68 + o] = W[i];
  }
  for (int i = tid; i < DN * 64; i += 256) {
    int node = i >> 6, c = i & 63;
    int n = base + node;
    sX[c * 130 + node] = (n < NN) ? h[(size_t)n * 64 + c] : 0.f;
  }
  __syncthreads();
  int j = tid & 63;
  int q = tid >> 6;
  float acc0[16], acc1[16];
#pragma unroll
  for (int o = 0; o < 16; ++o) { acc0[o] = b[q * 16 + o]; acc1[o] = acc0[o]; }
  for (int c = 0; c < 64; ++c) {
    float x0 = sX[c * 130 + j];
    float x1 = sX[c * 130 + 64 + j];
#pragma unroll
    for (int o4 = 0; o4 < 4; ++o4) {
      float4 wv = *(const float4*)&sWt[c * 68 + q * 16 + o4 * 4];
      acc0[o4 * 4 + 0] = fmaf(x0, wv.x, acc0[o4 * 4 + 0]);
      acc0[o4 * 4 + 1] = fmaf(x0, wv.y, acc0[o4 * 4 + 1]);
      acc0[o4 * 4 + 2] = fmaf(x0, wv.z, acc0[o4 * 4 + 2]);
      acc0[o4 * 4 + 3] = fmaf(x0, wv.w, acc0[o4 * 4 + 3]);
      acc1[o4 * 4 + 0] = fmaf(x1, wv.x, acc1[o4 * 4 + 0]);
      acc1[o4 * 4 + 1] = fmaf(x1, wv.y, acc1[o4 * 4 + 1]);
      acc1[o4 * 4 + 2] = fmaf(x1, wv.z, acc1[o4 * 4 + 2]);
      acc1[o4 * 4 + 3] = fmaf(x1, wv.w, acc1[o4 * 4 + 3]);
    }
  }
  int n0 = base + j, n1 = base + 64 + j;
#pragma unroll
  for (int half = 0; half < 2; ++half) {
    int n = half ? n1 : n0;
    float* acc = half ? acc1 : acc0;
    if (n < NN) {
#pragma unroll
      for (int o4 = 0; o4 < 4; ++o4) {
        float4 r;
        r.x = acc[o4 * 4 + 0]; r.y = acc[o4 * 4 + 1];
        r.z = acc[o4 * 4 + 2]; r.w = acc[o4 * 4 + 3];
        if (doRelu) {
          r.x = fmaxf(r.x, 0.f); r.y = fmaxf(r.y, 0.f);
          r.z = fmaxf(r.z, 0.f); r.w = fmaxf(r.w, 0.f);
        }
        if (doResid) {
          float4 rv = *(const float4*)&resid[(size_t)n * 64 + q * 16 + o4 * 4];
          r.x += rv.x; r.y += rv.y; r.z += rv.z; r.w += rv.w;
        }
        *(float4*)&out[(size_t)n * 64 + q * 16 + o4 * 4] = r;
      }
    }
  }
}

// ---------------- scoring / selection / output ----------------

__global__ void wp_norm(const float* __restrict__ wp, float* invn) {
  int lane = threadIdx.x;
  float v = wp[lane];
  float s = v * v;
#pragma unroll
  for (int o = 32; o > 0; o >>= 1) s += __shfl_xor(s, o);
  if (lane == 0) invn[0] = 1.0f / sqrtf(s);
}

__global__ __launch_bounds__(256) void score_k(const float* __restrict__ y,
                                               const float* __restrict__ wp,
                                               const float* __restrict__ invn,
                                               float* __restrict__ scores) {
  int tid = threadIdx.x;
  int lane = tid & 63, w = tid >> 6;
  int n = blockIdx.x * 4 + w;
  if (n >= NN) return;
  float p = y[(size_t)n * 64 + lane] * wp[lane];
#pragma unroll
  for (int o = 32; o > 0; o >>= 1) p += __shfl_xor(p, o);
  if (lane == 0) scores[n] = tanhf(p * invn[0]);
}

__device__ __forceinline__ bool lexgt(float v1, int i1, float v2, int i2) {
  return (v1 > v2) || (v1 == v2 && i1 < i2);
}

// phase 1: each of P1B blocks emits its local top-30 (argmax-and-remove in LDS)
__global__ __launch_bounds__(256) void topk_p1(const float* __restrict__ score,
                                               float* __restrict__ candv, int* __restrict__ candi) {
  __shared__ float sv[P1CH];
  __shared__ int si[P1CH];
  __shared__ float wvv[4];
  __shared__ int wii[4];
  __shared__ int wpp[4];
  int tid = threadIdx.x;
  int base = blockIdx.x * P1CH;
  for (int k = tid; k < P1CH; k += 256) {
    int idx = base + k;
    bool ok = idx < NN;
    sv[k] = ok ? score[idx] : -3.4e38f;
    si[k] = ok ? idx : 0x7FFFFFFF;
  }
  __syncthreads();
  for (int r = 0; r < TPK; ++r) {
    float bv = -3.4e38f; int bi = 0x7FFFFFFF; int bp = -1;
    for (int k = tid; k < P1CH; k += 256) {
      if (lexgt(sv[k], si[k], bv, bi)) { bv = sv[k]; bi = si[k]; bp = k; }
    }
#pragma unroll
    for (int o = 32; o > 0; o >>= 1) {
      float ov = __shfl_xor(bv, o); int oi = __shfl_xor(bi, o); int op = __shfl_xor(bp, o);
      if (lexgt(ov, oi, bv, bi)) { bv = ov; bi = oi; bp = op; }
    }
    if ((tid & 63) == 0) { int wl = tid >> 6; wvv[wl] = bv; wii[wl] = bi; wpp[wl] = bp; }
    __syncthreads();
    if (tid == 0) {
      float fv = wvv[0]; int fi = wii[0]; int fp = wpp[0];
#pragma unroll
      for (int u = 1; u < 4; ++u)
        if (lexgt(wvv[u], wii[u], fv, fi)) { fv = wvv[u]; fi = wii[u]; fp = wpp[u]; }
      candv[blockIdx.x * TPK + r] = fv;
      candi[blockIdx.x * TPK + r] = fi;
      if (fp >= 0) { sv[fp] = -3.4e38f; si[fp] = 0x7FFFFFFF; }
    }
    __syncthreads();
  }
}

// phase 2: merge P1B*30 candidates into the global top-30
__global__ __launch_bounds__(256) void topk_p2(const float* __restrict__ candv,
                                               const int* __restrict__ candi,
                                               int* __restrict__ sel_i, float* __restrict__ sel_v) {
  __shared__ float sv[P1B * TPK];
  __shared__ int si[P1B * TPK];
  __shared__ float wvv[4];
  __shared__ int wii[4];
  __shared__ int wpp[4];
  int tid = threadIdx.x;
  for (int k = tid; k < P1B * TPK; k += 256) { sv[k] = candv[k]; si[k] = candi[k]; }
  __syncthreads();
  for (int r = 0; r < TPK; ++r) {
    float bv = -3.4e38f; int bi = 0x7FFFFFFF; int bp = -1;
    for (int k = tid; k < P1B * TPK; k += 256) {
      if (lexgt(sv[k], si[k], bv, bi)) { bv = sv[k]; bi = si[k]; bp = k; }
    }
#pragma unroll
    for (int o = 32; o > 0; o >>= 1) {
      float ov = __shfl_xor(bv, o); int oi = __shfl_xor(bi, o); int op = __shfl_xor(bp, o);
      if (lexgt(ov, oi, bv, bi)) { bv = ov; bi = oi; bp = op; }
    }
    if ((tid & 63) == 0) { int wl = tid >> 6; wvv[wl] = bv; wii[wl] = bi; wpp[wl] = bp; }
    __syncthreads();
    if (tid == 0) {
      float fv = wvv[0]; int fi = wii[0]; int fp = wpp[0];
#pragma unroll
      for (int u = 1; u < 4; ++u)
        if (lexgt(wvv[u], wii[u], fv, fi)) { fv = wvv[u]; fi = wii[u]; fp = wpp[u]; }
      sel_v[r] = fv;
      sel_i[r] = fi;
      if (fp >= 0) { sv[fp] = -3.4e38f; si[fp] = 0x7FFFFFFF; }
    }
    __syncthreads();
  }
}

__global__ void final_max(const float* __restrict__ y, const int* __restrict__ sel_i,
                          const float* __restrict__ sel_v, float* __restrict__ out) {
  int c = threadIdx.x;  // 64 threads
  float m = -3.4e38f;
  for (int r = 0; r < TPK; ++r)
    m = fmaxf(m, y[(size_t)sel_i[r] * 64 + c] * sel_v[r]);
  out[c] = m;
}

// ---------------- host orchestration ----------------

extern "C" void kernel_launch(void* const* d_in, const int* in_sizes, int n_in,
                              void* d_out, int out_size, void* d_ws, size_t ws_size,
                              hipStream_t stream) {
  const float* x = (const float*)d_in[0];
  const int* ei = (const int*)d_in[1];
  const float* Wl[5] = {(const float*)d_in[2], (const float*)d_in[4], (const float*)d_in[6],
                        (const float*)d_in[8], (const float*)d_in[10]};
  const float* bl[5] = {(const float*)d_in[3], (const float*)d_in[5], (const float*)d_in[7],
                        (const float*)d_in[9], (const float*)d_in[11]};
  const float* Wm = (const float*)d_in[12];
  const float* bm = (const float*)d_in[13];
  const float* wp = (const float*)d_in[14];
  float* out = (float*)d_out;

  uint8_t* base = (uint8_t*)d_ws;
  size_t off = 0;
  auto alloc = [&](size_t bytes) -> void* {
    void* p = base + off;
    off += (bytes + 255) & ~(size_t)255;
    return p;
  };
  int* deg = (int*)alloc(NN * 4);
  int* rowptr = (int*)alloc((NN + 1) * 4);
  int* cursor = (int*)alloc(NN * 4);
  float* dinv = (float*)alloc(NN * 4);
  int* bsum = (int*)alloc(SCNB * 4);
  int* boff = (int*)alloc(SCNB * 4);
  int2* meta = (int2*)alloc((size_t)NNZ * 8);
  float* x0 = (float*)alloc((size_t)NN * 4 * 4);
  float* t4a = (float*)alloc((size_t)NN * 4 * 4);
  float* t4b = (float*)alloc((size_t)NN * 4 * 4);
  float* xcur = (float*)alloc((size_t)NN * 64 * 4);
  float* tA = (float*)alloc((size_t)NN * 64 * 4);
  float* tB = (float*)alloc((size_t)NN * 64 * 4);
  float* scores = (float*)alloc(NN * 4);
  float* invn = (float*)alloc(256);
  int* seli = (int*)alloc(TPK * 4);
  float* selv = (float*)alloc(TPK * 4);
  float* candv = (float*)alloc((size_t)P1B * TPK * 4);
  int* candi = (int*)alloc((size_t)P1B * TPK * 4);

  const int* erow = ei;
  const int* ecol = ei + EE;

  init_deg<<<(NN + 255) / 256, 256, 0, stream>>>(deg);
  count_deg<<<(EE + 255) / 256, 256, 0, stream>>>(ecol, deg);
  scan_bsum<<<SCNB, 256, 0, stream>>>(deg, bsum);
  scan_boff<<<1, 256, 0, stream>>>(bsum, boff);
  scan_write<<<SCNB, 256, 0, stream>>>(deg, boff, rowptr, cursor, dinv);
  scatter_csr<<<(NNZ + 255) / 256, 256, 0, stream>>>(erow, ecol, dinv, cursor, meta);
  extract_x0<<<(NN + 255) / 256, 256, 0, stream>>>(x, (float4*)x0);

  const float AL[5] = {0.7f, 0.7f, 0.35f, 0.7f / 3.0f, 0.175f};

  // layer 0 (cin = 4)
  {
    float coef = (1.0f - AL[0]) / (float)KK;
    const float* tin = x0;
    float* tout = t4a;
    for (int k = 1; k <= KK; ++k) {
      float aacc = (k == KK) ? coef : 1.0f;
      float axc = (k == KK) ? AL[0] : 1.0f;
      sweep4<<<(NN + 63) / 64, 256, 0, stream>>>((const float4*)tin, (const float4*)x0,
                                                 (float4*)tout, rowptr, meta, aacc, axc);
      tin = tout;
      tout = (tout == t4a) ? t4b : t4a;
    }
    dense4<<<(NN + 3) / 4, 256, 0, stream>>>(tin, Wl[0], bl[0], xcur);
  }
  // layers 1..4 (cin = 64)
  for (int l = 1; l < 5; ++l) {
    float coef = (1.0f - AL[l]) / (float)KK;
    const float* tin = xcur;
    float* tout = tA;
    for (int k = 1; k <= KK; ++k) {
      float aacc = (k == KK) ? coef : 1.0f;
      float axc = (k == KK) ? AL[l] : 1.0f;
      sweep64<<<(NN + 3) / 4, 256, 0, stream>>>((const float4*)tin, (const float4*)xcur,
                                                (float4*)tout, rowptr, meta, aacc, axc);
      tin = tout;
      tout = (tout == tA) ? tB : tA;
    }
    dense64<<<(NN + DN - 1) / DN, 256, 0, stream>>>(tin, Wl[l], bl[l], xcur, xcur, 1,
                                                    (l >= 2) ? 1 : 0);
  }
  // final projection y = x @ Wm.T + bm  -> tA
  dense64<<<(NN + DN - 1) / DN, 256, 0, stream>>>(xcur, Wm, bm, nullptr, tA, 0, 0);
  wp_norm<<<1, 64, 0, stream>>>(wp, invn);
  score_k<<<(NN + 3) / 4, 256, 0, stream>>>(tA, wp, invn, scores);
  topk_p1<<<P1B, 256, 0, stream>>>(scores, candv, candi);
  topk_p2<<<1, 256, 0, stream>>>(candv, candi, seli, selv);
  final_max<<<1, 64, 0, stream>>>(tA, seli, selv, out);
}

// Round 5
// 2813.468 us; speedup vs baseline: 1.6576x; 1.0891x over previous
//
#include <hip/hip_runtime.h>
#include <cstdint>
#include <cstddef>

#define NN 50000
#define EE 800000
#define NNZ (NN + EE)
#define KK 20
#define TPK 30
#define P1B 128
#define P1CH ((NN + P1B - 1) / P1B)  // 391
#define SCB 256
#define SCNB ((NN + SCB - 1) / SCB)  // 196

// ---------------- preprocessing ----------------

__global__ __launch_bounds__(256) void init_deg(int* deg) {
  int t = blockIdx.x * 256 + threadIdx.x;
  if (t < NN) deg[t] = 1;  // self-loop
}

__global__ __launch_bounds__(256) void count_deg(const int* __restrict__ ecol, int* deg) {
  int t = blockIdx.x * 256 + threadIdx.x;
  if (t < EE) atomicAdd(&deg[ecol[t]], 1);
}

__global__ __launch_bounds__(256) void scan_bsum(const int* __restrict__ deg, int* __restrict__ bsum) {
  __shared__ int red[256];
  int tid = threadIdx.x;
  int t = blockIdx.x * 256 + tid;
  red[tid] = (t < NN) ? deg[t] : 0;
  __syncthreads();
  for (int o = 128; o > 0; o >>= 1) {
    if (tid < o) red[tid] += red[tid + o];
    __syncthreads();
  }
  if (tid == 0) bsum[blockIdx.x] = red[0];
}

__global__ __launch_bounds__(256) void scan_boff(const int* __restrict__ bsum, int* __restrict__ boff) {
  __shared__ int s[256];
  int tid = threadIdx.x;
  int own = (tid < SCNB) ? bsum[tid] : 0;
  s[tid] = own;
  __syncthreads();
  for (int o = 1; o < 256; o <<= 1) {
    int v = s[tid];
    int u = (tid >= o) ? s[tid - o] : 0;
    __syncthreads();
    s[tid] = v + u;
    __syncthreads();
  }
  if (tid < SCNB) boff[tid] = s[tid] - own;  // exclusive
}

__global__ __launch_bounds__(256) void scan_write(const int* __restrict__ deg,
                                                  const int* __restrict__ boff,
                                                  int* __restrict__ rowptr, int* __restrict__ cursor,
                                                  float* __restrict__ dinv) {
  __shared__ int s[256];
  int tid = threadIdx.x;
  int t = blockIdx.x * 256 + tid;
  int d = (t < NN) ? deg[t] : 0;
  s[tid] = d;
  __syncthreads();
  for (int o = 1; o < 256; o <<= 1) {
    int v = s[tid];
    int u = (tid >= o) ? s[tid - o] : 0;
    __syncthreads();
    s[tid] = v + u;
    __syncthreads();
  }
  if (t < NN) {
    int excl = boff[blockIdx.x] + s[tid] - d;
    rowptr[t] = excl;
    cursor[t] = excl;
    dinv[t] = 1.0f / sqrtf((float)d);
    if (t == NN - 1) rowptr[NN] = excl + d;
  }
}

__global__ __launch_bounds__(256) void scatter_csr(const int* __restrict__ erow,
                                                   const int* __restrict__ ecol,
                                                   const float* __restrict__ dinv, int* cursor,
                                                   int2* __restrict__ meta) {
  int t = blockIdx.x * 256 + threadIdx.x;
  if (t < EE) {
    int r = erow[t], c = ecol[t];
    int p = atomicAdd(&cursor[c], 1);
    meta[p] = make_int2(r, __float_as_int(dinv[r] * dinv[c]));
  } else if (t < NNZ) {
    int i = t - EE;
    int p = atomicAdd(&cursor[i], 1);
    meta[p] = make_int2(i, __float_as_int(dinv[i] * dinv[i]));
  }
}

__global__ __launch_bounds__(256) void extract_x0(const float* __restrict__ x, float4* __restrict__ x0) {
  int t = blockIdx.x * 256 + threadIdx.x;
  if (t < NN) x0[t] = *(const float4*)&x[(size_t)t * 8];
}

// ---------------- propagation sweeps ----------------
// tout[v] = aacc * sum_e nrm[e]*tin[src[e]] + axc * xin[v]

// 64-channel: one wave per node. Lane-held metadata: one coalesced load round
// covers <=64 edge records, broadcast by shuffle. ALL inner-loop trip counts
// are wave-uniform (T = ceil(nj/4)); lanes >= nj hold (src=0, w=0.0f) so
// out-of-range slots contribute 0 — every __shfl runs with all 64 lanes
// active (divergent-shfl from inactive lanes is undefined on CDNA).
__global__ __launch_bounds__(256) void sweep64(const float4* __restrict__ tin,
                                               const float4* __restrict__ xin,
                                               float4* __restrict__ tout,
                                               const int* __restrict__ rowptr,
                                               const int2* __restrict__ meta,
                                               float aacc, float axc) {
  int lane = threadIdx.x & 63;
  int w = threadIdx.x >> 6;
  int v = blockIdx.x * 4 + w;
  if (v >= NN) return;  // wave-uniform (grid is exact for NN%4==0)
  int c16 = lane & 15;
  int e4 = lane >> 4;
  int s = rowptr[v], e = rowptr[v + 1];
  float4 xv = xin[(size_t)v * 16 + c16];  // hoisted: independent of edge loop
  float a0 = 0.f, a1 = 0.f, a2 = 0.f, a3 = 0.f;
  float b0 = 0.f, b1 = 0.f, b2 = 0.f, b3 = 0.f;
  for (int base = s; base < e; base += 64) {
    int nj = e - base;
    if (nj > 64) nj = 64;
    int2 mL = (lane < nj) ? meta[base + lane] : make_int2(0, 0);
    int T = (nj + 3) >> 2;  // wave-uniform trips; j = e4 + 4*t <= 63 always
    int t = 0, j = e4;
    for (; t + 3 < T; t += 4, j += 16) {
      int s0 = __shfl(mL.x, j);
      int s1 = __shfl(mL.x, j + 4);
      int s2 = __shfl(mL.x, j + 8);
      int s3 = __shfl(mL.x, j + 12);
      float w0 = __int_as_float(__shfl(mL.y, j));
      float w1 = __int_as_float(__shfl(mL.y, j + 4));
      float w2 = __int_as_float(__shfl(mL.y, j + 8));
      float w3 = __int_as_float(__shfl(mL.y, j + 12));
      float4 t0 = tin[(size_t)s0 * 16 + c16];
      float4 t1 = tin[(size_t)s1 * 16 + c16];
      float4 t2 = tin[(size_t)s2 * 16 + c16];
      float4 t3 = tin[(size_t)s3 * 16 + c16];
      a0 = fmaf(w0, t0.x, a0); a1 = fmaf(w0, t0.y, a1);
      a2 = fmaf(w0, t0.z, a2); a3 = fmaf(w0, t0.w, a3);
      b0 = fmaf(w1, t1.x, b0); b1 = fmaf(w1, t1.y, b1);
      b2 = fmaf(w1, t1.z, b2); b3 = fmaf(w1, t1.w, b3);
      a0 = fmaf(w2, t2.x, a0); a1 = fmaf(w2, t2.y, a1);
      a2 = fmaf(w2, t2.z, a2); a3 = fmaf(w2, t2.w, a3);
      b0 = fmaf(w3, t3.x, b0); b1 = fmaf(w3, t3.y, b1);
      b2 = fmaf(w3, t3.z, b2); b3 = fmaf(w3, t3.w, b3);
    }
    for (; t < T; ++t, j += 4) {
      int s0 = __shfl(mL.x, j);
      float w0 = __int_as_float(__shfl(mL.y, j));
      float4 t0 = tin[(size_t)s0 * 16 + c16];
      a0 = fmaf(w0, t0.x, a0); a1 = fmaf(w0, t0.y, a1);
      a2 = fmaf(w0, t0.z, a2); a3 = fmaf(w0, t0.w, a3);
    }
  }
  a0 += b0; a1 += b1; a2 += b2; a3 += b3;
  a0 += __shfl_xor(a0, 16); a1 += __shfl_xor(a1, 16);
  a2 += __shfl_xor(a2, 16); a3 += __shfl_xor(a3, 16);
  a0 += __shfl_xor(a0, 32); a1 += __shfl_xor(a1, 32);
  a2 += __shfl_xor(a2, 32); a3 += __shfl_xor(a3, 32);
  if (e4 == 0) {
    float4 o;
    o.x = aacc * a0 + axc * xv.x;
    o.y = aacc * a1 + axc * xv.y;
    o.z = aacc * a2 + axc * xv.z;
    o.w = aacc * a3 + axc * xv.w;
    tout[(size_t)v * 16 + c16] = o;
  }
}

// 4-channel: wave = 16 nodes x 4 edge slots; unrolled x4 (no in-loop shuffles,
// so per-lane divergence is safe; reductions happen after reconvergence).
__global__ __launch_bounds__(256) void sweep4(const float4* __restrict__ tin,
                                              const float4* __restrict__ xin,
                                              float4* __restrict__ tout,
                                              const int* __restrict__ rowptr,
                                              const int2* __restrict__ meta,
                                              float aacc, float axc) {
  int lane = threadIdx.x & 63;
  int w = threadIdx.x >> 6;
  int n16 = lane & 15;
  int e4 = lane >> 4;
  int v = (blockIdx.x * 4 + w) * 16 + n16;
  int vv = (v < NN) ? v : (NN - 1);
  int s = rowptr[vv], e = rowptr[vv + 1];
  float a0 = 0.f, a1 = 0.f, a2 = 0.f, a3 = 0.f;
  float b0 = 0.f, b1 = 0.f, b2 = 0.f, b3 = 0.f;
  int i = s + e4;
  for (; i + 12 < e; i += 16) {
    int2 m0 = meta[i];
    int2 m1 = meta[i + 4];
    int2 m2 = meta[i + 8];
    int2 m3 = meta[i + 12];
    float w0 = __int_as_float(m0.y);
    float w1 = __int_as_float(m1.y);
    float w2 = __int_as_float(m2.y);
    float w3 = __int_as_float(m3.y);
    float4 t0 = tin[m0.x];
    float4 t1 = tin[m1.x];
    float4 t2 = tin[m2.x];
    float4 t3 = tin[m3.x];
    a0 = fmaf(w0, t0.x, a0); a1 = fmaf(w0, t0.y, a1);
    a2 = fmaf(w0, t0.z, a2); a3 = fmaf(w0, t0.w, a3);
    b0 = fmaf(w1, t1.x, b0); b1 = fmaf(w1, t1.y, b1);
    b2 = fmaf(w1, t1.z, b2); b3 = fmaf(w1, t1.w, b3);
    a0 = fmaf(w2, t2.x, a0); a1 = fmaf(w2, t2.y, a1);
    a2 = fmaf(w2, t2.z, a2); a3 = fmaf(w2, t2.w, a3);
    b0 = fmaf(w3, t3.x, b0); b1 = fmaf(w3, t3.y, b1);
    b2 = fmaf(w3, t3.z, b2); b3 = fmaf(w3, t3.w, b3);
  }
  for (; i < e; i += 4) {
    int2 m0 = meta[i];
    float w0 = __int_as_float(m0.y);
    float4 t0 = tin[m0.x];
    a0 = fmaf(w0, t0.x, a0); a1 = fmaf(w0, t0.y, a1);
    a2 = fmaf(w0, t0.z, a2); a3 = fmaf(w0, t0.w, a3);
  }
  a0 += b0; a1 += b1; a2 += b2; a3 += b3;
  a0 += __shfl_xor(a0, 16); a1 += __shfl_xor(a1, 16);
  a2 += __shfl_xor(a2, 16); a3 += __shfl_xor(a3, 16);
  a0 += __shfl_xor(a0, 32); a1 += __shfl_xor(a1, 32);
  a2 += __shfl_xor(a2, 32); a3 += __shfl_xor(a3, 32);
  if (e4 == 0 && v < NN) {
    float4 xv = xin[v];
    float4 o;
    o.x = aacc * a0 + axc * xv.x;
    o.y = aacc * a1 + axc * xv.y;
    o.z = aacc * a2 + axc * xv.z;
    o.w = aacc * a3 + axc * xv.w;
    tout[v] = o;
  }
}

// ---------------- dense layers ----------------

__global__ __launch_bounds__(256) void dense4(const float* __restrict__ h4,
                                              const float* __restrict__ W,  // [64][4]
                                              const float* __restrict__ b,
                                              float* __restrict__ out) {
  __shared__ float sWt[4 * 64];
  int tid = threadIdx.x;
  {
    int j = tid >> 2, c = tid & 3;
    sWt[c * 64 + j] = W[tid];
  }
  __syncthreads();
  int lane = tid & 63, w = tid >> 6;
  int n = blockIdx.x * 4 + w;
  if (n >= NN) return;
  float acc = b[lane];
#pragma unroll
  for (int c = 0; c < 4; ++c)
    acc = fmaf(h4[(size_t)n * 4 + c], sWt[c * 64 + lane], acc);
  acc = fmaxf(acc, 0.f);
  out[(size_t)n * 64 + lane] = acc;
}

// 128 nodes per block; thread = (node j, out-quarter q) covering nodes {j, j+64}, outs [16q,16q+16)
#define DN 128
__global__ __launch_bounds__(256) void dense64(const float* __restrict__ h,
                                               const float* __restrict__ W,  // [64][64]
                                               const float* __restrict__ b,
                                               const float* __restrict__ resid,
                                               float* __restrict__ out,
                                               int doRelu, int doResid) {
  __shared__ float sX[64 * 130];   // [c][node], stride 130 -> 2-way (free)
  __shared__ float sWt[64 * 68];   // [c][out], stride 68 -> b128-aligned rows
  int tid = threadIdx.x;
  int base = blockIdx.x * DN;
  for (int i = tid; i < 64 * 64; i += 256) {
    int o = i >> 6, c = i & 63;
    sWt[c * 68 + o] = W[i];
  }
  for (int i = tid; i < DN * 64; i += 256) {
    int node = i >> 6, c = i & 63;
    int n = base + node;
    sX[c * 130 + node] = (n < NN) ? h[(size_t)n * 64 + c] : 0.f;
  }
  __syncthreads();
  int j = tid & 63;
  int q = tid >> 6;
  float acc0[16], acc1[16];
#pragma unroll
  for (int o = 0; o < 16; ++o) { acc0[o] = b[q * 16 + o]; acc1[o] = acc0[o]; }
  for (int c = 0; c < 64; ++c) {
    float x0 = sX[c * 130 + j];
    float x1 = sX[c * 130 + 64 + j];
#pragma unroll
    for (int o4 = 0; o4 < 4; ++o4) {
      float4 wv = *(const float4*)&sWt[c * 68 + q * 16 + o4 * 4];
      acc0[o4 * 4 + 0] = fmaf(x0, wv.x, acc0[o4 * 4 + 0]);
      acc0[o4 * 4 + 1] = fmaf(x0, wv.y, acc0[o4 * 4 + 1]);
      acc0[o4 * 4 + 2] = fmaf(x0, wv.z, acc0[o4 * 4 + 2]);
      acc0[o4 * 4 + 3] = fmaf(x0, wv.w, acc0[o4 * 4 + 3]);
      acc1[o4 * 4 + 0] = fmaf(x1, wv.x, acc1[o4 * 4 + 0]);
      acc1[o4 * 4 + 1] = fmaf(x1, wv.y, acc1[o4 * 4 + 1]);
      acc1[o4 * 4 + 2] = fmaf(x1, wv.z, acc1[o4 * 4 + 2]);
      acc1[o4 * 4 + 3] = fmaf(x1, wv.w, acc1[o4 * 4 + 3]);
    }
  }
  int n0 = base + j, n1 = base + 64 + j;
#pragma unroll
  for (int half = 0; half < 2; ++half) {
    int n = half ? n1 : n0;
    float* acc = half ? acc1 : acc0;
    if (n < NN) {
#pragma unroll
      for (int o4 = 0; o4 < 4; ++o4) {
        float4 r;
        r.x = acc[o4 * 4 + 0]; r.y = acc[o4 * 4 + 1];
        r.z = acc[o4 * 4 + 2]; r.w = acc[o4 * 4 + 3];
        if (doRelu) {
          r.x = fmaxf(r.x, 0.f); r.y = fmaxf(r.y, 0.f);
          r.z = fmaxf(r.z, 0.f); r.w = fmaxf(r.w, 0.f);
        }
        if (doResid) {
          float4 rv = *(const float4*)&resid[(size_t)n * 64 + q * 16 + o4 * 4];
          r.x += rv.x; r.y += rv.y; r.z += rv.z; r.w += rv.w;
        }
        *(float4*)&out[(size_t)n * 64 + q * 16 + o4 * 4] = r;
      }
    }
  }
}

// ---------------- scoring / selection / output ----------------

__global__ void wp_norm(const float* __restrict__ wp, float* invn) {
  int lane = threadIdx.x;
  float v = wp[lane];
  float s = v * v;
#pragma unroll
  for (int o = 32; o > 0; o >>= 1) s += __shfl_xor(s, o);
  if (lane == 0) invn[0] = 1.0f / sqrtf(s);
}

__global__ __launch_bounds__(256) void score_k(const float* __restrict__ y,
                                               const float* __restrict__ wp,
                                               const float* __restrict__ invn,
                                               float* __restrict__ scores) {
  int tid = threadIdx.x;
  int lane = tid & 63, w = tid >> 6;
  int n = blockIdx.x * 4 + w;
  if (n >= NN) return;
  float p = y[(size_t)n * 64 + lane] * wp[lane];
#pragma unroll
  for (int o = 32; o > 0; o >>= 1) p += __shfl_xor(p, o);
  if (lane == 0) scores[n] = tanhf(p * invn[0]);
}

__device__ __forceinline__ bool lexgt(float v1, int i1, float v2, int i2) {
  return (v1 > v2) || (v1 == v2 && i1 < i2);
}

// phase 1: each of P1B blocks emits its local top-30 (argmax-and-remove in LDS)
__global__ __launch_bounds__(256) void topk_p1(const float* __restrict__ score,
                                               float* __restrict__ candv, int* __restrict__ candi) {
  __shared__ float sv[P1CH];
  __shared__ int si[P1CH];
  __shared__ float wvv[4];
  __shared__ int wii[4];
  __shared__ int wpp[4];
  int tid = threadIdx.x;
  int base = blockIdx.x * P1CH;
  for (int k = tid; k < P1CH; k += 256) {
    int idx = base + k;
    bool ok = idx < NN;
    sv[k] = ok ? score[idx] : -3.4e38f;
    si[k] = ok ? idx : 0x7FFFFFFF;
  }
  __syncthreads();
  for (int r = 0; r < TPK; ++r) {
    float bv = -3.4e38f; int bi = 0x7FFFFFFF; int bp = -1;
    for (int k = tid; k < P1CH; k += 256) {
      if (lexgt(sv[k], si[k], bv, bi)) { bv = sv[k]; bi = si[k]; bp = k; }
    }
#pragma unroll
    for (int o = 32; o > 0; o >>= 1) {
      float ov = __shfl_xor(bv, o); int oi = __shfl_xor(bi, o); int op = __shfl_xor(bp, o);
      if (lexgt(ov, oi, bv, bi)) { bv = ov; bi = oi; bp = op; }
    }
    if ((tid & 63) == 0) { int wl = tid >> 6; wvv[wl] = bv; wii[wl] = bi; wpp[wl] = bp; }
    __syncthreads();
    if (tid == 0) {
      float fv = wvv[0]; int fi = wii[0]; int fp = wpp[0];
#pragma unroll
      for (int u = 1; u < 4; ++u)
        if (lexgt(wvv[u], wii[u], fv, fi)) { fv = wvv[u]; fi = wii[u]; fp = wpp[u]; }
      candv[blockIdx.x * TPK + r] = fv;
      candi[blockIdx.x * TPK + r] = fi;
      if (fp >= 0) { sv[fp] = -3.4e38f; si[fp] = 0x7FFFFFFF; }
    }
    __syncthreads();
  }
}

// phase 2: merge P1B*30 candidates into the global top-30 (1024 threads)
__global__ __launch_bounds__(1024) void topk_p2(const float* __restrict__ candv,
                                                const int* __restrict__ candi,
                                                int* __restrict__ sel_i, float* __restrict__ sel_v) {
  __shared__ float sv[P1B * TPK];
  __shared__ int si[P1B * TPK];
  __shared__ float wvv[16];
  __shared__ int wii[16];
  __shared__ int wpp[16];
  int tid = threadIdx.x;
  for (int k = tid; k < P1B * TPK; k += 1024) { sv[k] = candv[k]; si[k] = candi[k]; }
  __syncthreads();
  for (int r = 0; r < TPK; ++r) {
    float bv = -3.4e38f; int bi = 0x7FFFFFFF; int bp = -1;
    for (int k = tid; k < P1B * TPK; k += 1024) {
      if (lexgt(sv[k], si[k], bv, bi)) { bv = sv[k]; bi = si[k]; bp = k; }
    }
#pragma unroll
    for (int o = 32; o > 0; o >>= 1) {
      float ov = __shfl_xor(bv, o); int oi = __shfl_xor(bi, o); int op = __shfl_xor(bp, o);
      if (lexgt(ov, oi, bv, bi)) { bv = ov; bi = oi; bp = op; }
    }
    if ((tid & 63) == 0) { int wl = tid >> 6; wvv[wl] = bv; wii[wl] = bi; wpp[wl] = bp; }
    __syncthreads();
    if (tid == 0) {
      float fv = wvv[0]; int fi = wii[0]; int fp = wpp[0];
#pragma unroll
      for (int u = 1; u < 16; ++u)
        if (lexgt(wvv[u], wii[u], fv, fi)) { fv = wvv[u]; fi = wii[u]; fp = wpp[u]; }
      sel_v[r] = fv;
      sel_i[r] = fi;
      if (fp >= 0) { sv[fp] = -3.4e38f; si[fp] = 0x7FFFFFFF; }
    }
    __syncthreads();
  }
}

__global__ void final_max(const float* __restrict__ y, const int* __restrict__ sel_i,
                          const float* __restrict__ sel_v, float* __restrict__ out) {
  int c = threadIdx.x;  // 64 threads
  float m = -3.4e38f;
  for (int r = 0; r < TPK; ++r)
    m = fmaxf(m, y[(size_t)sel_i[r] * 64 + c] * sel_v[r]);
  out[c] = m;
}

// ---------------- host orchestration ----------------

extern "C" void kernel_launch(void* const* d_in, const int* in_sizes, int n_in,
                              void* d_out, int out_size, void* d_ws, size_t ws_size,
                              hipStream_t stream) {
  const float* x = (const float*)d_in[0];
  const int* ei = (const int*)d_in[1];
  const float* Wl[5] = {(const float*)d_in[2], (const float*)d_in[4], (const float*)d_in[6],
                        (const float*)d_in[8], (const float*)d_in[10]};
  const float* bl[5] = {(const float*)d_in[3], (const float*)d_in[5], (const float*)d_in[7],
                        (const float*)d_in[9], (const float*)d_in[11]};
  const float* Wm = (const float*)d_in[12];
  const float* bm = (const float*)d_in[13];
  const float* wp = (const float*)d_in[14];
  float* out = (float*)d_out;

  uint8_t* base = (uint8_t*)d_ws;
  size_t off = 0;
  auto alloc = [&](size_t bytes) -> void* {
    void* p = base + off;
    off += (bytes + 255) & ~(size_t)255;
    return p;
  };
  int* deg = (int*)alloc(NN * 4);
  int* rowptr = (int*)alloc((NN + 1) * 4);
  int* cursor = (int*)alloc(NN * 4);
  float* dinv = (float*)alloc(NN * 4);
  int* bsum = (int*)alloc(SCNB * 4);
  int* boff = (int*)alloc(SCNB * 4);
  int2* meta = (int2*)alloc((size_t)NNZ * 8);
  float* x0 = (float*)alloc((size_t)NN * 4 * 4);
  float* t4a = (float*)alloc((size_t)NN * 4 * 4);
  float* t4b = (float*)alloc((size_t)NN * 4 * 4);
  float* xcur = (float*)alloc((size_t)NN * 64 * 4);
  float* tA = (float*)alloc((size_t)NN * 64 * 4);
  float* tB = (float*)alloc((size_t)NN * 64 * 4);
  float* scores = (float*)alloc(NN * 4);
  float* invn = (float*)alloc(256);
  int* seli = (int*)alloc(TPK * 4);
  float* selv = (float*)alloc(TPK * 4);
  float* candv = (float*)alloc((size_t)P1B * TPK * 4);
  int* candi = (int*)alloc((size_t)P1B * TPK * 4);

  const int* erow = ei;
  const int* ecol = ei + EE;

  init_deg<<<(NN + 255) / 256, 256, 0, stream>>>(deg);
  count_deg<<<(EE + 255) / 256, 256, 0, stream>>>(ecol, deg);
  scan_bsum<<<SCNB, 256, 0, stream>>>(deg, bsum);
  scan_boff<<<1, 256, 0, stream>>>(bsum, boff);
  scan_write<<<SCNB, 256, 0, stream>>>(deg, boff, rowptr, cursor, dinv);
  scatter_csr<<<(NNZ + 255) / 256, 256, 0, stream>>>(erow, ecol, dinv, cursor, meta);
  extract_x0<<<(NN + 255) / 256, 256, 0, stream>>>(x, (float4*)x0);

  const float AL[5] = {0.7f, 0.7f, 0.35f, 0.7f / 3.0f, 0.175f};

  // layer 0 (cin = 4)
  {
    float coef = (1.0f - AL[0]) / (float)KK;
    const float* tin = x0;
    float* tout = t4a;
    for (int k = 1; k <= KK; ++k) {
      float aacc = (k == KK) ? coef : 1.0f;
      float axc = (k == KK) ? AL[0] : 1.0f;
      sweep4<<<(NN + 63) / 64, 256, 0, stream>>>((const float4*)tin, (const float4*)x0,
                                                 (float4*)tout, rowptr, meta, aacc, axc);
      tin = tout;
      tout = (tout == t4a) ? t4b : t4a;
    }
    dense4<<<(NN + 3) / 4, 256, 0, stream>>>(tin, Wl[0], bl[0], xcur);
  }
  // layers 1..4 (cin = 64)
  for (int l = 1; l < 5; ++l) {
    float coef = (1.0f - AL[l]) / (float)KK;
    const float* tin = xcur;
    float* tout = tA;
    for (int k = 1; k <= KK; ++k) {
      float aacc = (k == KK) ? coef : 1.0f;
      float axc = (k == KK) ? AL[l] : 1.0f;
      sweep64<<<(NN + 3) / 4, 256, 0, stream>>>((const float4*)tin, (const float4*)xcur,
                                                (float4*)tout, rowptr, meta, aacc, axc);
      tin = tout;
      tout = (tout == tA) ? tB : tA;
    }
    dense64<<<(NN + DN - 1) / DN, 256, 0, stream>>>(tin, Wl[l], bl[l], xcur, xcur, 1,
                                                    (l >= 2) ? 1 : 0);
  }
  // final projection y = x @ Wm.T + bm  -> tA
  dense64<<<(NN + DN - 1) / DN, 256, 0, stream>>>(xcur, Wm, bm, nullptr, tA, 0, 0);
  wp_norm<<<1, 64, 0, stream>>>(wp, invn);
  score_k<<<(NN + 3) / 4, 256, 0, stream>>>(tA, wp, invn, scores);
  topk_p1<<<P1B, 256, 0, stream>>>(scores, candv, candi);
  topk_p2<<<1, 1024, 0, stream>>>(candv, candi, seli, selv);
  final_max<<<1, 64, 0, stream>>>(tA, seli, selv, out);
}

// Round 6
// 2243.158 us; speedup vs baseline: 2.0791x; 1.2542x over previous
//
#include <hip/hip_runtime.h>
#include <hip/hip_fp16.h>
#include <cstdint>
#include <cstddef>

#define NN 50000
#define EE 800000
#define NNZ (NN + EE)
#define KK 20
#define TPK 30
#define P1B 128
#define P1CH ((NN + P1B - 1) / P1B)  // 391
#define SCB 256
#define SCNB ((NN + SCB - 1) / SCB)  // 196

// ---------------- fp16 helpers ----------------

__device__ __forceinline__ float2 h2f(unsigned int u) {
  __half2 h = *reinterpret_cast<__half2*>(&u);
  return __half22float2(h);
}
__device__ __forceinline__ unsigned int f2h(float a, float b) {
  __half2 h = __floats2half2_rn(a, b);
  return *reinterpret_cast<unsigned int*>(&h);
}

// ---------------- preprocessing ----------------

__global__ __launch_bounds__(256) void init_deg(int* deg) {
  int t = blockIdx.x * 256 + threadIdx.x;
  if (t < NN) deg[t] = 1;  // self-loop
}

__global__ __launch_bounds__(256) void count_deg(const int* __restrict__ ecol, int* deg) {
  int t = blockIdx.x * 256 + threadIdx.x;
  if (t < EE) atomicAdd(&deg[ecol[t]], 1);
}

__global__ __launch_bounds__(256) void scan_bsum(const int* __restrict__ deg, int* __restrict__ bsum) {
  __shared__ int red[256];
  int tid = threadIdx.x;
  int t = blockIdx.x * 256 + tid;
  red[tid] = (t < NN) ? deg[t] : 0;
  __syncthreads();
  for (int o = 128; o > 0; o >>= 1) {
    if (tid < o) red[tid] += red[tid + o];
    __syncthreads();
  }
  if (tid == 0) bsum[blockIdx.x] = red[0];
}

__global__ __launch_bounds__(256) void scan_boff(const int* __restrict__ bsum, int* __restrict__ boff) {
  __shared__ int s[256];
  int tid = threadIdx.x;
  int own = (tid < SCNB) ? bsum[tid] : 0;
  s[tid] = own;
  __syncthreads();
  for (int o = 1; o < 256; o <<= 1) {
    int v = s[tid];
    int u = (tid >= o) ? s[tid - o] : 0;
    __syncthreads();
    s[tid] = v + u;
    __syncthreads();
  }
  if (tid < SCNB) boff[tid] = s[tid] - own;  // exclusive
}

__global__ __launch_bounds__(256) void scan_write(const int* __restrict__ deg,
                                                  const int* __restrict__ boff,
                                                  int* __restrict__ rowptr, int* __restrict__ cursor,
                                                  float* __restrict__ dinv) {
  __shared__ int s[256];
  int tid = threadIdx.x;
  int t = blockIdx.x * 256 + tid;
  int d = (t < NN) ? deg[t] : 0;
  s[tid] = d;
  __syncthreads();
  for (int o = 1; o < 256; o <<= 1) {
    int v = s[tid];
    int u = (tid >= o) ? s[tid - o] : 0;
    __syncthreads();
    s[tid] = v + u;
    __syncthreads();
  }
  if (t < NN) {
    int excl = boff[blockIdx.x] + s[tid] - d;
    rowptr[t] = excl;
    cursor[t] = excl;
    dinv[t] = 1.0f / sqrtf((float)d);
    if (t == NN - 1) rowptr[NN] = excl + d;
  }
}

__global__ __launch_bounds__(256) void scatter_csr(const int* __restrict__ erow,
                                                   const int* __restrict__ ecol,
                                                   const float* __restrict__ dinv, int* cursor,
                                                   int2* __restrict__ meta) {
  int t = blockIdx.x * 256 + threadIdx.x;
  if (t < EE) {
    int r = erow[t], c = ecol[t];
    int p = atomicAdd(&cursor[c], 1);
    meta[p] = make_int2(r, __float_as_int(dinv[r] * dinv[c]));
  } else if (t < NNZ) {
    int i = t - EE;
    int p = atomicAdd(&cursor[i], 1);
    meta[p] = make_int2(i, __float_as_int(dinv[i] * dinv[i]));
  }
}

__global__ __launch_bounds__(256) void extract_x0(const float* __restrict__ x, float4* __restrict__ x0) {
  int t = blockIdx.x * 256 + threadIdx.x;
  if (t < NN) x0[t] = *(const float4*)&x[(size_t)t * 8];
}

// f32 rows -> fp16 rows (8 floats per thread)
__global__ __launch_bounds__(256) void half_cast(const float4* __restrict__ in,
                                                 uint4* __restrict__ out) {
  int t = blockIdx.x * 256 + threadIdx.x;
  if (t < NN * 8) {
    float4 f0 = in[(size_t)t * 2];
    float4 f1 = in[(size_t)t * 2 + 1];
    uint4 r;
    r.x = f2h(f0.x, f0.y);
    r.y = f2h(f0.z, f0.w);
    r.z = f2h(f1.x, f1.y);
    r.w = f2h(f1.z, f1.w);
    out[t] = r;
  }
}

// ---------------- propagation sweeps ----------------
// tout[v] = aacc * sum_e nrm[e]*tin[src[e]] + axc * xin[v]

// 64-channel fp16 sweep: one wave per node; lane = (e8 edge-slot, c8 = 8 channels).
// fp16 rows are 128B: one uint4 load = 8 channels; one instruction = 8 edges.
// Lane-held meta broadcast by shuffle; ALL trip counts wave-uniform; lanes >= nj
// hold (src=0, w=0) so every __shfl runs with all 64 lanes active.
__global__ __launch_bounds__(256) void sweep64h(const uint4* __restrict__ tinq,   // fp16 state
                                                const uint4* __restrict__ xinq,   // fp16 x (non-final)
                                                const float4* __restrict__ xinf,  // f32 x (final)
                                                uint4* __restrict__ touth,        // fp16 out
                                                float4* __restrict__ toutf,       // f32 out (final)
                                                const int* __restrict__ rowptr,
                                                const int2* __restrict__ meta,
                                                float aacc, float axc, int isFinal) {
  int lane = threadIdx.x & 63;
  int w = threadIdx.x >> 6;
  int v = blockIdx.x * 4 + w;
  if (v >= NN) return;  // wave-uniform (NN % 4 == 0, grid exact)
  int c8 = lane & 7;
  int e8 = lane >> 3;
  int s = rowptr[v], e = rowptr[v + 1];
  float a0 = 0.f, a1 = 0.f, a2 = 0.f, a3 = 0.f;
  float a4 = 0.f, a5 = 0.f, a6 = 0.f, a7 = 0.f;
  for (int base = s; base < e; base += 64) {
    int nj = e - base;
    if (nj > 64) nj = 64;
    int2 mL = (lane < nj) ? meta[base + lane] : make_int2(0, 0);
    int T = (nj + 7) >> 3;  // wave-uniform; j = e8 + 8t <= 63 always
    int t = 0;
    for (; t + 1 < T; t += 2) {
      int j0 = e8 + 8 * t;
      int j1 = j0 + 8;
      int s0 = __shfl(mL.x, j0);
      int s1 = __shfl(mL.x, j1);
      float w0 = __int_as_float(__shfl(mL.y, j0));
      float w1 = __int_as_float(__shfl(mL.y, j1));
      uint4 q0 = tinq[(size_t)s0 * 8 + c8];
      uint4 q1 = tinq[(size_t)s1 * 8 + c8];
      float2 f;
      f = h2f(q0.x); a0 = fmaf(w0, f.x, a0); a1 = fmaf(w0, f.y, a1);
      f = h2f(q0.y); a2 = fmaf(w0, f.x, a2); a3 = fmaf(w0, f.y, a3);
      f = h2f(q0.z); a4 = fmaf(w0, f.x, a4); a5 = fmaf(w0, f.y, a5);
      f = h2f(q0.w); a6 = fmaf(w0, f.x, a6); a7 = fmaf(w0, f.y, a7);
      f = h2f(q1.x); a0 = fmaf(w1, f.x, a0); a1 = fmaf(w1, f.y, a1);
      f = h2f(q1.y); a2 = fmaf(w1, f.x, a2); a3 = fmaf(w1, f.y, a3);
      f = h2f(q1.z); a4 = fmaf(w1, f.x, a4); a5 = fmaf(w1, f.y, a5);
      f = h2f(q1.w); a6 = fmaf(w1, f.x, a6); a7 = fmaf(w1, f.y, a7);
    }
    if (t < T) {
      int j0 = e8 + 8 * t;
      int s0 = __shfl(mL.x, j0);
      float w0 = __int_as_float(__shfl(mL.y, j0));
      uint4 q0 = tinq[(size_t)s0 * 8 + c8];
      float2 f;
      f = h2f(q0.x); a0 = fmaf(w0, f.x, a0); a1 = fmaf(w0, f.y, a1);
      f = h2f(q0.y); a2 = fmaf(w0, f.x, a2); a3 = fmaf(w0, f.y, a3);
      f = h2f(q0.z); a4 = fmaf(w0, f.x, a4); a5 = fmaf(w0, f.y, a5);
      f = h2f(q0.w); a6 = fmaf(w0, f.x, a6); a7 = fmaf(w0, f.y, a7);
    }
  }
  // reduce across the 8 e-slots (lane bits 3..5)
#pragma unroll
  for (int o = 8; o <= 32; o <<= 1) {
    a0 += __shfl_xor(a0, o); a1 += __shfl_xor(a1, o);
    a2 += __shfl_xor(a2, o); a3 += __shfl_xor(a3, o);
    a4 += __shfl_xor(a4, o); a5 += __shfl_xor(a5, o);
    a6 += __shfl_xor(a6, o); a7 += __shfl_xor(a7, o);
  }
  if (e8 == 0) {
    if (isFinal) {
      float4 x0v = xinf[(size_t)v * 16 + c8 * 2];
      float4 x1v = xinf[(size_t)v * 16 + c8 * 2 + 1];
      float4 r0, r1;
      r0.x = aacc * a0 + axc * x0v.x; r0.y = aacc * a1 + axc * x0v.y;
      r0.z = aacc * a2 + axc * x0v.z; r0.w = aacc * a3 + axc * x0v.w;
      r1.x = aacc * a4 + axc * x1v.x; r1.y = aacc * a5 + axc * x1v.y;
      r1.z = aacc * a6 + axc * x1v.z; r1.w = aacc * a7 + axc * x1v.w;
      toutf[(size_t)v * 16 + c8 * 2] = r0;
      toutf[(size_t)v * 16 + c8 * 2 + 1] = r1;
    } else {
      uint4 xq = xinq[(size_t)v * 8 + c8];
      float2 f;
      f = h2f(xq.x); float o0 = a0 + f.x, o1 = a1 + f.y;
      f = h2f(xq.y); float o2 = a2 + f.x, o3 = a3 + f.y;
      f = h2f(xq.z); float o4 = a4 + f.x, o5 = a5 + f.y;
      f = h2f(xq.w); float o6 = a6 + f.x, o7 = a7 + f.y;
      uint4 r;
      r.x = f2h(o0, o1); r.y = f2h(o2, o3);
      r.z = f2h(o4, o5); r.w = f2h(o6, o7);
      touth[(size_t)v * 8 + c8] = r;
    }
  }
}

// 4-channel f32: wave = 16 nodes x 4 edge slots; unrolled x4 (no in-loop shuffles).
__global__ __launch_bounds__(256) void sweep4(const float4* __restrict__ tin,
                                              const float4* __restrict__ xin,
                                              float4* __restrict__ tout,
                                              const int* __restrict__ rowptr,
                                              const int2* __restrict__ meta,
                                              float aacc, float axc) {
  int lane = threadIdx.x & 63;
  int w = threadIdx.x >> 6;
  int n16 = lane & 15;
  int e4 = lane >> 4;
  int v = (blockIdx.x * 4 + w) * 16 + n16;
  int vv = (v < NN) ? v : (NN - 1);
  int s = rowptr[vv], e = rowptr[vv + 1];
  float a0 = 0.f, a1 = 0.f, a2 = 0.f, a3 = 0.f;
  float b0 = 0.f, b1 = 0.f, b2 = 0.f, b3 = 0.f;
  int i = s + e4;
  for (; i + 12 < e; i += 16) {
    int2 m0 = meta[i];
    int2 m1 = meta[i + 4];
    int2 m2 = meta[i + 8];
    int2 m3 = meta[i + 12];
    float w0 = __int_as_float(m0.y);
    float w1 = __int_as_float(m1.y);
    float w2 = __int_as_float(m2.y);
    float w3 = __int_as_float(m3.y);
    float4 t0 = tin[m0.x];
    float4 t1 = tin[m1.x];
    float4 t2 = tin[m2.x];
    float4 t3 = tin[m3.x];
    a0 = fmaf(w0, t0.x, a0); a1 = fmaf(w0, t0.y, a1);
    a2 = fmaf(w0, t0.z, a2); a3 = fmaf(w0, t0.w, a3);
    b0 = fmaf(w1, t1.x, b0); b1 = fmaf(w1, t1.y, b1);
    b2 = fmaf(w1, t1.z, b2); b3 = fmaf(w1, t1.w, b3);
    a0 = fmaf(w2, t2.x, a0); a1 = fmaf(w2, t2.y, a1);
    a2 = fmaf(w2, t2.z, a2); a3 = fmaf(w2, t2.w, a3);
    b0 = fmaf(w3, t3.x, b0); b1 = fmaf(w3, t3.y, b1);
    b2 = fmaf(w3, t3.z, b2); b3 = fmaf(w3, t3.w, b3);
  }
  for (; i < e; i += 4) {
    int2 m0 = meta[i];
    float w0 = __int_as_float(m0.y);
    float4 t0 = tin[m0.x];
    a0 = fmaf(w0, t0.x, a0); a1 = fmaf(w0, t0.y, a1);
    a2 = fmaf(w0, t0.z, a2); a3 = fmaf(w0, t0.w, a3);
  }
  a0 += b0; a1 += b1; a2 += b2; a3 += b3;
  a0 += __shfl_xor(a0, 16); a1 += __shfl_xor(a1, 16);
  a2 += __shfl_xor(a2, 16); a3 += __shfl_xor(a3, 16);
  a0 += __shfl_xor(a0, 32); a1 += __shfl_xor(a1, 32);
  a2 += __shfl_xor(a2, 32); a3 += __shfl_xor(a3, 32);
  if (e4 == 0 && v < NN) {
    float4 xv = xin[v];
    float4 o;
    o.x = aacc * a0 + axc * xv.x;
    o.y = aacc * a1 + axc * xv.y;
    o.z = aacc * a2 + axc * xv.z;
    o.w = aacc * a3 + axc * xv.w;
    tout[v] = o;
  }
}

// ---------------- dense layers ----------------

__global__ __launch_bounds__(256) void dense4(const float* __restrict__ h4,
                                              const float* __restrict__ W,  // [64][4]
                                              const float* __restrict__ b,
                                              float* __restrict__ out) {
  __shared__ float sWt[4 * 64];
  int tid = threadIdx.x;
  {
    int j = tid >> 2, c = tid & 3;
    sWt[c * 64 + j] = W[tid];
  }
  __syncthreads();
  int lane = tid & 63, w = tid >> 6;
  int n = blockIdx.x * 4 + w;
  if (n >= NN) return;
  float acc = b[lane];
#pragma unroll
  for (int c = 0; c < 4; ++c)
    acc = fmaf(h4[(size_t)n * 4 + c], sWt[c * 64 + lane], acc);
  acc = fmaxf(acc, 0.f);
  out[(size_t)n * 64 + lane] = acc;
}

// 128 nodes per block; thread = (node j, out-quarter q) covering nodes {j, j+64}
#define DN 128
__global__ __launch_bounds__(256) void dense64(const float* __restrict__ h,
                                               const float* __restrict__ W,  // [64][64]
                                               const float* __restrict__ b,
                                               const float* __restrict__ resid,
                                               float* __restrict__ out,
                                               int doRelu, int doResid) {
  __shared__ float sX[64 * 130];
  __shared__ float sWt[64 * 68];
  int tid = threadIdx.x;
  int base = blockIdx.x * DN;
  for (int i = tid; i < 64 * 64; i += 256) {
    int o = i >> 6, c = i & 63;
    sWt[c * 68 + o] = W[i];
  }
  for (int i = tid; i < DN * 64; i += 256) {
    int node = i >> 6, c = i & 63;
    int n = base + node;
    sX[c * 130 + node] = (n < NN) ? h[(size_t)n * 64 + c] : 0.f;
  }
  __syncthreads();
  int j = tid & 63;
  int q = tid >> 6;
  float acc0[16], acc1[16];
#pragma unroll
  for (int o = 0; o < 16; ++o) { acc0[o] = b[q * 16 + o]; acc1[o] = acc0[o]; }
  for (int c = 0; c < 64; ++c) {
    float x0 = sX[c * 130 + j];
    float x1 = sX[c * 130 + 64 + j];
#pragma unroll
    for (int o4 = 0; o4 < 4; ++o4) {
      float4 wv = *(const float4*)&sWt[c * 68 + q * 16 + o4 * 4];
      acc0[o4 * 4 + 0] = fmaf(x0, wv.x, acc0[o4 * 4 + 0]);
      acc0[o4 * 4 + 1] = fmaf(x0, wv.y, acc0[o4 * 4 + 1]);
      acc0[o4 * 4 + 2] = fmaf(x0, wv.z, acc0[o4 * 4 + 2]);
      acc0[o4 * 4 + 3] = fmaf(x0, wv.w, acc0[o4 * 4 + 3]);
      acc1[o4 * 4 + 0] = fmaf(x1, wv.x, acc1[o4 * 4 + 0]);
      acc1[o4 * 4 + 1] = fmaf(x1, wv.y, acc1[o4 * 4 + 1]);
      acc1[o4 * 4 + 2] = fmaf(x1, wv.z, acc1[o4 * 4 + 2]);
      acc1[o4 * 4 + 3] = fmaf(x1, wv.w, acc1[o4 * 4 + 3]);
    }
  }
  int n0 = base + j, n1 = base + 64 + j;
#pragma unroll
  for (int half = 0; half < 2; ++half) {
    int n = half ? n1 : n0;
    float* acc = half ? acc1 : acc0;
    if (n < NN) {
#pragma unroll
      for (int o4 = 0; o4 < 4; ++o4) {
        float4 r;
        r.x = acc[o4 * 4 + 0]; r.y = acc[o4 * 4 + 1];
        r.z = acc[o4 * 4 + 2]; r.w = acc[o4 * 4 + 3];
        if (doRelu) {
          r.x = fmaxf(r.x, 0.f); r.y = fmaxf(r.y, 0.f);
          r.z = fmaxf(r.z, 0.f); r.w = fmaxf(r.w, 0.f);
        }
        if (doResid) {
          float4 rv = *(const float4*)&resid[(size_t)n * 64 + q * 16 + o4 * 4];
          r.x += rv.x; r.y += rv.y; r.z += rv.z; r.w += rv.w;
        }
        *(float4*)&out[(size_t)n * 64 + q * 16 + o4 * 4] = r;
      }
    }
  }
}

// ---------------- scoring / selection / output ----------------

__global__ void wp_norm(const float* __restrict__ wp, float* invn) {
  int lane = threadIdx.x;
  float v = wp[lane];
  float s = v * v;
#pragma unroll
  for (int o = 32; o > 0; o >>= 1) s += __shfl_xor(s, o);
  if (lane == 0) invn[0] = 1.0f / sqrtf(s);
}

__global__ __launch_bounds__(256) void score_k(const float* __restrict__ y,
                                               const float* __restrict__ wp,
                                               const float* __restrict__ invn,
                                               float* __restrict__ scores) {
  int tid = threadIdx.x;
  int lane = tid & 63, w = tid >> 6;
  int n = blockIdx.x * 4 + w;
  if (n >= NN) return;
  float p = y[(size_t)n * 64 + lane] * wp[lane];
#pragma unroll
  for (int o = 32; o > 0; o >>= 1) p += __shfl_xor(p, o);
  if (lane == 0) scores[n] = tanhf(p * invn[0]);
}

__device__ __forceinline__ bool lexgt(float v1, int i1, float v2, int i2) {
  return (v1 > v2) || (v1 == v2 && i1 < i2);
}

// phase 1: each of P1B blocks emits its local top-30
__global__ __launch_bounds__(256) void topk_p1(const float* __restrict__ score,
                                               float* __restrict__ candv, int* __restrict__ candi) {
  __shared__ float sv[P1CH];
  __shared__ int si[P1CH];
  __shared__ float wvv[4];
  __shared__ int wii[4];
  __shared__ int wpp[4];
  int tid = threadIdx.x;
  int base = blockIdx.x * P1CH;
  for (int k = tid; k < P1CH; k += 256) {
    int idx = base + k;
    bool ok = idx < NN;
    sv[k] = ok ? score[idx] : -3.4e38f;
    si[k] = ok ? idx : 0x7FFFFFFF;
  }
  __syncthreads();
  for (int r = 0; r < TPK; ++r) {
    float bv = -3.4e38f; int bi = 0x7FFFFFFF; int bp = -1;
    for (int k = tid; k < P1CH; k += 256) {
      if (lexgt(sv[k], si[k], bv, bi)) { bv = sv[k]; bi = si[k]; bp = k; }
    }
#pragma unroll
    for (int o = 32; o > 0; o >>= 1) {
      float ov = __shfl_xor(bv, o); int oi = __shfl_xor(bi, o); int op = __shfl_xor(bp, o);
      if (lexgt(ov, oi, bv, bi)) { bv = ov; bi = oi; bp = op; }
    }
    if ((tid & 63) == 0) { int wl = tid >> 6; wvv[wl] = bv; wii[wl] = bi; wpp[wl] = bp; }
    __syncthreads();
    if (tid == 0) {
      float fv = wvv[0]; int fi = wii[0]; int fp = wpp[0];
#pragma unroll
      for (int u = 1; u < 4; ++u)
        if (lexgt(wvv[u], wii[u], fv, fi)) { fv = wvv[u]; fi = wii[u]; fp = wpp[u]; }
      candv[blockIdx.x * TPK + r] = fv;
      candi[blockIdx.x * TPK + r] = fi;
      if (fp >= 0) { sv[fp] = -3.4e38f; si[fp] = 0x7FFFFFFF; }
    }
    __syncthreads();
  }
}

// phase 2: single-wave register merge of P1B*30 candidates (no barriers).
// Each lane holds a sorted top-30 chain (static indices only); 30 rounds of
// wave argmax over chain heads + predicated full shift on the winning lane.
__global__ void topk_p2(const float* __restrict__ candv, const int* __restrict__ candi,
                        int* __restrict__ sel_i, float* __restrict__ sel_v) {
  int lane = threadIdx.x;  // 64
  float lv[TPK]; int li[TPK];
#pragma unroll
  for (int k = 0; k < TPK; ++k) { lv[k] = -3.4e38f; li[k] = 0x7FFFFFFF; }
  for (int k = lane; k < P1B * TPK; k += 64) {
    float v = candv[k]; int id = candi[k];
    if (lexgt(v, id, lv[TPK - 1], li[TPK - 1])) {
      float cv = v; int ci = id;
#pragma unroll
      for (int m = 0; m < TPK; ++m) {
        bool sw = lexgt(cv, ci, lv[m], li[m]);
        float tv = sw ? lv[m] : cv; int ti = sw ? li[m] : ci;
        lv[m] = sw ? cv : lv[m]; li[m] = sw ? ci : li[m];
        cv = tv; ci = ti;
      }
    }
  }
  for (int r = 0; r < TPK; ++r) {
    float bv = lv[0]; int bi = li[0];
#pragma unroll
    for (int o = 32; o > 0; o >>= 1) {
      float ov = __shfl_xor(bv, o); int oi = __shfl_xor(bi, o);
      if (lexgt(ov, oi, bv, bi)) { bv = ov; bi = oi; }
    }
    if (lane == 0) { sel_v[r] = bv; sel_i[r] = bi; }
    bool mine = (li[0] == bi) && (lv[0] == bv);  // indices unique -> one winner
#pragma unroll
    for (int m = 0; m < TPK - 1; ++m) {
      lv[m] = mine ? lv[m + 1] : lv[m];
      li[m] = mine ? li[m + 1] : li[m];
    }
    if (mine) { lv[TPK - 1] = -3.4e38f; li[TPK - 1] = 0x7FFFFFFF; }
  }
}

__global__ void final_max(const float* __restrict__ y, const int* __restrict__ sel_i,
                          const float* __restrict__ sel_v, float* __restrict__ out) {
  int c = threadIdx.x;  // 64 threads
  float m = -3.4e38f;
  for (int r = 0; r < TPK; ++r)
    m = fmaxf(m, y[(size_t)sel_i[r] * 64 + c] * sel_v[r]);
  out[c] = m;
}

// ---------------- host orchestration ----------------

extern "C" void kernel_launch(void* const* d_in, const int* in_sizes, int n_in,
                              void* d_out, int out_size, void* d_ws, size_t ws_size,
                              hipStream_t stream) {
  const float* x = (const float*)d_in[0];
  const int* ei = (const int*)d_in[1];
  const float* Wl[5] = {(const float*)d_in[2], (const float*)d_in[4], (const float*)d_in[6],
                        (const float*)d_in[8], (const float*)d_in[10]};
  const float* bl[5] = {(const float*)d_in[3], (const float*)d_in[5], (const float*)d_in[7],
                        (const float*)d_in[9], (const float*)d_in[11]};
  const float* Wm = (const float*)d_in[12];
  const float* bm = (const float*)d_in[13];
  const float* wp = (const float*)d_in[14];
  float* out = (float*)d_out;

  uint8_t* base = (uint8_t*)d_ws;
  size_t off = 0;
  auto alloc = [&](size_t bytes) -> void* {
    void* p = base + off;
    off += (bytes + 255) & ~(size_t)255;
    return p;
  };
  int* deg = (int*)alloc(NN * 4);
  int* rowptr = (int*)alloc((NN + 1) * 4);
  int* cursor = (int*)alloc(NN * 4);
  float* dinv = (float*)alloc(NN * 4);
  int* bsum = (int*)alloc(SCNB * 4);
  int* boff = (int*)alloc(SCNB * 4);
  int2* meta = (int2*)alloc((size_t)NNZ * 8);
  float* x0 = (float*)alloc((size_t)NN * 4 * 4);
  float* t4a = (float*)alloc((size_t)NN * 4 * 4);
  float* t4b = (float*)alloc((size_t)NN * 4 * 4);
  float* xcur = (float*)alloc((size_t)NN * 64 * 4);
  float* tA = (float*)alloc((size_t)NN * 64 * 4);
  uint4* xh = (uint4*)alloc((size_t)NN * 64 * 2);   // fp16 x copy
  uint4* thA = (uint4*)alloc((size_t)NN * 64 * 2);  // fp16 state ping
  uint4* thB = (uint4*)alloc((size_t)NN * 64 * 2);  // fp16 state pong
  float* scores = (float*)alloc(NN * 4);
  float* invn = (float*)alloc(256);
  int* seli = (int*)alloc(TPK * 4);
  float* selv = (float*)alloc(TPK * 4);
  float* candv = (float*)alloc((size_t)P1B * TPK * 4);
  int* candi = (int*)alloc((size_t)P1B * TPK * 4);

  const int* erow = ei;
  const int* ecol = ei + EE;

  init_deg<<<(NN + 255) / 256, 256, 0, stream>>>(deg);
  count_deg<<<(EE + 255) / 256, 256, 0, stream>>>(ecol, deg);
  scan_bsum<<<SCNB, 256, 0, stream>>>(deg, bsum);
  scan_boff<<<1, 256, 0, stream>>>(bsum, boff);
  scan_write<<<SCNB, 256, 0, stream>>>(deg, boff, rowptr, cursor, dinv);
  scatter_csr<<<(NNZ + 255) / 256, 256, 0, stream>>>(erow, ecol, dinv, cursor, meta);
  extract_x0<<<(NN + 255) / 256, 256, 0, stream>>>(x, (float4*)x0);

  const float AL[5] = {0.7f, 0.7f, 0.35f, 0.7f / 3.0f, 0.175f};

  // layer 0 (cin = 4, f32 — footprint is L2-resident)
  {
    float coef = (1.0f - AL[0]) / (float)KK;
    const float* tin = x0;
    float* tout = t4a;
    for (int k = 1; k <= KK; ++k) {
      float aacc = (k == KK) ? coef : 1.0f;
      float axc = (k == KK) ? AL[0] : 1.0f;
      sweep4<<<(NN + 63) / 64, 256, 0, stream>>>((const float4*)tin, (const float4*)x0,
                                                 (float4*)tout, rowptr, meta, aacc, axc);
      tin = tout;
      tout = (tout == t4a) ? t4b : t4a;
    }
    dense4<<<(NN + 3) / 4, 256, 0, stream>>>(tin, Wl[0], bl[0], xcur);
  }
  // layers 1..4 (cin = 64, fp16 propagation state)
  for (int l = 1; l < 5; ++l) {
    float coef = (1.0f - AL[l]) / (float)KK;
    half_cast<<<(NN * 8 + 255) / 256, 256, 0, stream>>>((const float4*)xcur, xh);
    const uint4* tin = xh;
    uint4* tout = thA;
    for (int k = 1; k < KK; ++k) {
      sweep64h<<<(NN + 3) / 4, 256, 0, stream>>>(tin, xh, nullptr, tout, nullptr, rowptr, meta,
                                                 1.0f, 1.0f, 0);
      tin = tout;
      tout = (tout == thA) ? thB : thA;
    }
    // final sweep: gather fp16, combine with f32 x, write f32
    sweep64h<<<(NN + 3) / 4, 256, 0, stream>>>(tin, nullptr, (const float4*)xcur, nullptr,
                                               (float4*)tA, rowptr, meta, coef, AL[l], 1);
    dense64<<<(NN + DN - 1) / DN, 256, 0, stream>>>(tA, Wl[l], bl[l], xcur, xcur, 1,
                                                    (l >= 2) ? 1 : 0);
  }
  // final projection y = x @ Wm.T + bm  -> tA
  dense64<<<(NN + DN - 1) / DN, 256, 0, stream>>>(xcur, Wm, bm, nullptr, tA, 0, 0);
  wp_norm<<<1, 64, 0, stream>>>(wp, invn);
  score_k<<<(NN + 3) / 4, 256, 0, stream>>>(tA, wp, invn, scores);
  topk_p1<<<P1B, 256, 0, stream>>>(scores, candv, candi);
  topk_p2<<<1, 64, 0, stream>>>(candv, candi, seli, selv);
  final_max<<<1, 64, 0, stream>>>(tA, seli, selv, out);
}

// Round 7
// 2196.160 us; speedup vs baseline: 2.1236x; 1.0214x over previous
//
#include <hip/hip_runtime.h>
#include <hip/hip_fp16.h>
#include <cstdint>
#include <cstddef>

#define NN 50000
#define EE 800000
#define NNZ (NN + EE)
#define KK 20
#define TPK 30
#define P1B 64
#define P1CH ((NN + P1B - 1) / P1B)  // 782
#define SCB 256
#define SCNB ((NN + SCB - 1) / SCB)  // 196

// ---------------- fp16 helpers ----------------

__device__ __forceinline__ float2 h2f(unsigned int u) {
  __half2 h = *reinterpret_cast<__half2*>(&u);
  return __half22float2(h);
}
__device__ __forceinline__ unsigned int f2h(float a, float b) {
  __half2 h = __floats2half2_rn(a, b);
  return *reinterpret_cast<unsigned int*>(&h);
}

// ---------------- preprocessing ----------------

__global__ __launch_bounds__(256) void init_deg(int* deg) {
  int t = blockIdx.x * 256 + threadIdx.x;
  if (t < NN) deg[t] = 1;  // self-loop
}

__global__ __launch_bounds__(256) void count_deg(const int* __restrict__ ecol, int* deg) {
  int t = blockIdx.x * 256 + threadIdx.x;
  if (t < EE) atomicAdd(&deg[ecol[t]], 1);
}

__global__ __launch_bounds__(256) void scan_bsum(const int* __restrict__ deg, int* __restrict__ bsum) {
  __shared__ int red[256];
  int tid = threadIdx.x;
  int t = blockIdx.x * 256 + tid;
  red[tid] = (t < NN) ? deg[t] : 0;
  __syncthreads();
  for (int o = 128; o > 0; o >>= 1) {
    if (tid < o) red[tid] += red[tid + o];
    __syncthreads();
  }
  if (tid == 0) bsum[blockIdx.x] = red[0];
}

__global__ __launch_bounds__(256) void scan_boff(const int* __restrict__ bsum, int* __restrict__ boff) {
  __shared__ int s[256];
  int tid = threadIdx.x;
  int own = (tid < SCNB) ? bsum[tid] : 0;
  s[tid] = own;
  __syncthreads();
  for (int o = 1; o < 256; o <<= 1) {
    int v = s[tid];
    int u = (tid >= o) ? s[tid - o] : 0;
    __syncthreads();
    s[tid] = v + u;
    __syncthreads();
  }
  if (tid < SCNB) boff[tid] = s[tid] - own;  // exclusive
}

__global__ __launch_bounds__(256) void scan_write(const int* __restrict__ deg,
                                                  const int* __restrict__ boff,
                                                  int* __restrict__ rowptr, int* __restrict__ cursor,
                                                  float* __restrict__ dinv) {
  __shared__ int s[256];
  int tid = threadIdx.x;
  int t = blockIdx.x * 256 + tid;
  int d = (t < NN) ? deg[t] : 0;
  s[tid] = d;
  __syncthreads();
  for (int o = 1; o < 256; o <<= 1) {
    int v = s[tid];
    int u = (tid >= o) ? s[tid - o] : 0;
    __syncthreads();
    s[tid] = v + u;
    __syncthreads();
  }
  if (t < NN) {
    int excl = boff[blockIdx.x] + s[tid] - d;
    rowptr[t] = excl;
    cursor[t] = excl;
    dinv[t] = 1.0f / sqrtf((float)d);
    if (t == NN - 1) rowptr[NN] = excl + d;
  }
}

__global__ __launch_bounds__(256) void scatter_csr(const int* __restrict__ erow,
                                                   const int* __restrict__ ecol,
                                                   const float* __restrict__ dinv, int* cursor,
                                                   int2* __restrict__ meta) {
  int t = blockIdx.x * 256 + threadIdx.x;
  if (t < EE) {
    int r = erow[t], c = ecol[t];
    int p = atomicAdd(&cursor[c], 1);
    meta[p] = make_int2(r, __float_as_int(dinv[r] * dinv[c]));
  } else if (t < NNZ) {
    int i = t - EE;
    int p = atomicAdd(&cursor[i], 1);
    meta[p] = make_int2(i, __float_as_int(dinv[i] * dinv[i]));
  }
}

__global__ __launch_bounds__(256) void extract_x0(const float* __restrict__ x, float4* __restrict__ x0) {
  int t = blockIdx.x * 256 + threadIdx.x;
  if (t < NN) x0[t] = *(const float4*)&x[(size_t)t * 8];
}

// ---------------- propagation sweeps ----------------
// tout[v] = aacc * sum_e nrm[e]*tin[src[e]] + axc * xin[v]

// 64-channel fp16 sweep: one wave per node; lane = (e8 edge-slot, c8 = 8 channels).
// Lane-held meta broadcast by shuffle; ALL trip counts wave-uniform; lanes >= nj
// hold (src=0, w=0) so every __shfl runs with all 64 lanes active.
__global__ __launch_bounds__(256) void sweep64h(const uint4* __restrict__ tinq,   // fp16 state
                                                const uint4* __restrict__ xinq,   // fp16 x (non-final)
                                                const float4* __restrict__ xinf,  // f32 x (final)
                                                uint4* __restrict__ touth,        // fp16 out
                                                float4* __restrict__ toutf,       // f32 out (final)
                                                const int* __restrict__ rowptr,
                                                const int2* __restrict__ meta,
                                                float aacc, float axc, int isFinal) {
  int lane = threadIdx.x & 63;
  int w = threadIdx.x >> 6;
  int v = blockIdx.x * 4 + w;
  if (v >= NN) return;  // wave-uniform (NN % 4 == 0, grid exact)
  int c8 = lane & 7;
  int e8 = lane >> 3;
  int s = rowptr[v], e = rowptr[v + 1];
  float a0 = 0.f, a1 = 0.f, a2 = 0.f, a3 = 0.f;
  float a4 = 0.f, a5 = 0.f, a6 = 0.f, a7 = 0.f;
  for (int base = s; base < e; base += 64) {
    int nj = e - base;
    if (nj > 64) nj = 64;
    int2 mL = (lane < nj) ? meta[base + lane] : make_int2(0, 0);
    int T = (nj + 7) >> 3;  // wave-uniform; j = e8 + 8t <= 63 always
    int t = 0;
    for (; t + 1 < T; t += 2) {
      int j0 = e8 + 8 * t;
      int j1 = j0 + 8;
      int s0 = __shfl(mL.x, j0);
      int s1 = __shfl(mL.x, j1);
      float w0 = __int_as_float(__shfl(mL.y, j0));
      float w1 = __int_as_float(__shfl(mL.y, j1));
      uint4 q0 = tinq[(size_t)s0 * 8 + c8];
      uint4 q1 = tinq[(size_t)s1 * 8 + c8];
      float2 f;
      f = h2f(q0.x); a0 = fmaf(w0, f.x, a0); a1 = fmaf(w0, f.y, a1);
      f = h2f(q0.y); a2 = fmaf(w0, f.x, a2); a3 = fmaf(w0, f.y, a3);
      f = h2f(q0.z); a4 = fmaf(w0, f.x, a4); a5 = fmaf(w0, f.y, a5);
      f = h2f(q0.w); a6 = fmaf(w0, f.x, a6); a7 = fmaf(w0, f.y, a7);
      f = h2f(q1.x); a0 = fmaf(w1, f.x, a0); a1 = fmaf(w1, f.y, a1);
      f = h2f(q1.y); a2 = fmaf(w1, f.x, a2); a3 = fmaf(w1, f.y, a3);
      f = h2f(q1.z); a4 = fmaf(w1, f.x, a4); a5 = fmaf(w1, f.y, a5);
      f = h2f(q1.w); a6 = fmaf(w1, f.x, a6); a7 = fmaf(w1, f.y, a7);
    }
    if (t < T) {
      int j0 = e8 + 8 * t;
      int s0 = __shfl(mL.x, j0);
      float w0 = __int_as_float(__shfl(mL.y, j0));
      uint4 q0 = tinq[(size_t)s0 * 8 + c8];
      float2 f;
      f = h2f(q0.x); a0 = fmaf(w0, f.x, a0); a1 = fmaf(w0, f.y, a1);
      f = h2f(q0.y); a2 = fmaf(w0, f.x, a2); a3 = fmaf(w0, f.y, a3);
      f = h2f(q0.z); a4 = fmaf(w0, f.x, a4); a5 = fmaf(w0, f.y, a5);
      f = h2f(q0.w); a6 = fmaf(w0, f.x, a6); a7 = fmaf(w0, f.y, a7);
    }
  }
  // reduce across the 8 e-slots (lane bits 3..5)
#pragma unroll
  for (int o = 8; o <= 32; o <<= 1) {
    a0 += __shfl_xor(a0, o); a1 += __shfl_xor(a1, o);
    a2 += __shfl_xor(a2, o); a3 += __shfl_xor(a3, o);
    a4 += __shfl_xor(a4, o); a5 += __shfl_xor(a5, o);
    a6 += __shfl_xor(a6, o); a7 += __shfl_xor(a7, o);
  }
  if (e8 == 0) {
    if (isFinal) {
      float4 x0v = xinf[(size_t)v * 16 + c8 * 2];
      float4 x1v = xinf[(size_t)v * 16 + c8 * 2 + 1];
      float4 r0, r1;
      r0.x = aacc * a0 + axc * x0v.x; r0.y = aacc * a1 + axc * x0v.y;
      r0.z = aacc * a2 + axc * x0v.z; r0.w = aacc * a3 + axc * x0v.w;
      r1.x = aacc * a4 + axc * x1v.x; r1.y = aacc * a5 + axc * x1v.y;
      r1.z = aacc * a6 + axc * x1v.z; r1.w = aacc * a7 + axc * x1v.w;
      toutf[(size_t)v * 16 + c8 * 2] = r0;
      toutf[(size_t)v * 16 + c8 * 2 + 1] = r1;
    } else {
      uint4 xq = xinq[(size_t)v * 8 + c8];
      float2 f;
      f = h2f(xq.x); float o0 = a0 + f.x, o1 = a1 + f.y;
      f = h2f(xq.y); float o2 = a2 + f.x, o3 = a3 + f.y;
      f = h2f(xq.z); float o4 = a4 + f.x, o5 = a5 + f.y;
      f = h2f(xq.w); float o6 = a6 + f.x, o7 = a7 + f.y;
      uint4 r;
      r.x = f2h(o0, o1); r.y = f2h(o2, o3);
      r.z = f2h(o4, o5); r.w = f2h(o6, o7);
      touth[(size_t)v * 8 + c8] = r;
    }
  }
}

// 4-channel f32: wave = 16 nodes x 4 edge slots; unrolled x4 (no in-loop shuffles).
__global__ __launch_bounds__(256) void sweep4(const float4* __restrict__ tin,
                                              const float4* __restrict__ xin,
                                              float4* __restrict__ tout,
                                              const int* __restrict__ rowptr,
                                              const int2* __restrict__ meta,
                                              float aacc, float axc) {
  int lane = threadIdx.x & 63;
  int w = threadIdx.x >> 6;
  int n16 = lane & 15;
  int e4 = lane >> 4;
  int v = (blockIdx.x * 4 + w) * 16 + n16;
  int vv = (v < NN) ? v : (NN - 1);
  int s = rowptr[vv], e = rowptr[vv + 1];
  float a0 = 0.f, a1 = 0.f, a2 = 0.f, a3 = 0.f;
  float b0 = 0.f, b1 = 0.f, b2 = 0.f, b3 = 0.f;
  int i = s + e4;
  for (; i + 12 < e; i += 16) {
    int2 m0 = meta[i];
    int2 m1 = meta[i + 4];
    int2 m2 = meta[i + 8];
    int2 m3 = meta[i + 12];
    float w0 = __int_as_float(m0.y);
    float w1 = __int_as_float(m1.y);
    float w2 = __int_as_float(m2.y);
    float w3 = __int_as_float(m3.y);
    float4 t0 = tin[m0.x];
    float4 t1 = tin[m1.x];
    float4 t2 = tin[m2.x];
    float4 t3 = tin[m3.x];
    a0 = fmaf(w0, t0.x, a0); a1 = fmaf(w0, t0.y, a1);
    a2 = fmaf(w0, t0.z, a2); a3 = fmaf(w0, t0.w, a3);
    b0 = fmaf(w1, t1.x, b0); b1 = fmaf(w1, t1.y, b1);
    b2 = fmaf(w1, t1.z, b2); b3 = fmaf(w1, t1.w, b3);
    a0 = fmaf(w2, t2.x, a0); a1 = fmaf(w2, t2.y, a1);
    a2 = fmaf(w2, t2.z, a2); a3 = fmaf(w2, t2.w, a3);
    b0 = fmaf(w3, t3.x, b0); b1 = fmaf(w3, t3.y, b1);
    b2 = fmaf(w3, t3.z, b2); b3 = fmaf(w3, t3.w, b3);
  }
  for (; i < e; i += 4) {
    int2 m0 = meta[i];
    float w0 = __int_as_float(m0.y);
    float4 t0 = tin[m0.x];
    a0 = fmaf(w0, t0.x, a0); a1 = fmaf(w0, t0.y, a1);
    a2 = fmaf(w0, t0.z, a2); a3 = fmaf(w0, t0.w, a3);
  }
  a0 += b0; a1 += b1; a2 += b2; a3 += b3;
  a0 += __shfl_xor(a0, 16); a1 += __shfl_xor(a1, 16);
  a2 += __shfl_xor(a2, 16); a3 += __shfl_xor(a3, 16);
  a0 += __shfl_xor(a0, 32); a1 += __shfl_xor(a1, 32);
  a2 += __shfl_xor(a2, 32); a3 += __shfl_xor(a3, 32);
  if (e4 == 0 && v < NN) {
    float4 xv = xin[v];
    float4 o;
    o.x = aacc * a0 + axc * xv.x;
    o.y = aacc * a1 + axc * xv.y;
    o.z = aacc * a2 + axc * xv.z;
    o.w = aacc * a3 + axc * xv.w;
    tout[v] = o;
  }
}

// ---------------- dense layers ----------------

// emits f32 out AND (optionally) fp16 copy for the next layer's propagation
__global__ __launch_bounds__(256) void dense4(const float* __restrict__ h4,
                                              const float* __restrict__ W,  // [64][4]
                                              const float* __restrict__ b,
                                              float* __restrict__ out,
                                              unsigned int* __restrict__ outh) {
  __shared__ float sWt[4 * 64];
  int tid = threadIdx.x;
  {
    int j = tid >> 2, c = tid & 3;
    sWt[c * 64 + j] = W[tid];
  }
  __syncthreads();
  int lane = tid & 63, w = tid >> 6;
  int n = blockIdx.x * 4 + w;
  if (n >= NN) return;  // wave-uniform
  float acc = b[lane];
#pragma unroll
  for (int c = 0; c < 4; ++c)
    acc = fmaf(h4[(size_t)n * 4 + c], sWt[c * 64 + lane], acc);
  acc = fmaxf(acc, 0.f);
  out[(size_t)n * 64 + lane] = acc;
  // fp16 pair write: all 64 lanes shuffle (uniform), lanes 0..31 store
  int p = lane & 31;
  float va = __shfl(acc, 2 * p);
  float vb = __shfl(acc, 2 * p + 1);
  if (lane < 32) outh[(size_t)n * 32 + lane] = f2h(va, vb);
}

// 128 nodes per block; thread = (node j, out-quarter q) covering nodes {j, j+64}
#define DN 128
__global__ __launch_bounds__(256) void dense64(const float* __restrict__ h,
                                               const float* __restrict__ W,  // [64][64]
                                               const float* __restrict__ b,
                                               const float* __restrict__ resid,
                                               float* __restrict__ out,
                                               uint4* __restrict__ outh,  // optional fp16 copy
                                               int doRelu, int doResid) {
  __shared__ float sX[64 * 130];
  __shared__ float sWt[64 * 68];
  int tid = threadIdx.x;
  int base = blockIdx.x * DN;
  for (int i = tid; i < 64 * 64; i += 256) {
    int o = i >> 6, c = i & 63;
    sWt[c * 68 + o] = W[i];
  }
  for (int i = tid; i < DN * 64; i += 256) {
    int node = i >> 6, c = i & 63;
    int n = base + node;
    sX[c * 130 + node] = (n < NN) ? h[(size_t)n * 64 + c] : 0.f;
  }
  __syncthreads();
  int j = tid & 63;
  int q = tid >> 6;
  float acc0[16], acc1[16];
#pragma unroll
  for (int o = 0; o < 16; ++o) { acc0[o] = b[q * 16 + o]; acc1[o] = acc0[o]; }
  for (int c = 0; c < 64; ++c) {
    float x0 = sX[c * 130 + j];
    float x1 = sX[c * 130 + 64 + j];
#pragma unroll
    for (int o4 = 0; o4 < 4; ++o4) {
      float4 wv = *(const float4*)&sWt[c * 68 + q * 16 + o4 * 4];
      acc0[o4 * 4 + 0] = fmaf(x0, wv.x, acc0[o4 * 4 + 0]);
      acc0[o4 * 4 + 1] = fmaf(x0, wv.y, acc0[o4 * 4 + 1]);
      acc0[o4 * 4 + 2] = fmaf(x0, wv.z, acc0[o4 * 4 + 2]);
      acc0[o4 * 4 + 3] = fmaf(x0, wv.w, acc0[o4 * 4 + 3]);
      acc1[o4 * 4 + 0] = fmaf(x1, wv.x, acc1[o4 * 4 + 0]);
      acc1[o4 * 4 + 1] = fmaf(x1, wv.y, acc1[o4 * 4 + 1]);
      acc1[o4 * 4 + 2] = fmaf(x1, wv.z, acc1[o4 * 4 + 2]);
      acc1[o4 * 4 + 3] = fmaf(x1, wv.w, acc1[o4 * 4 + 3]);
    }
  }
  int n0 = base + j, n1 = base + 64 + j;
#pragma unroll
  for (int half = 0; half < 2; ++half) {
    int n = half ? n1 : n0;
    float* acc = half ? acc1 : acc0;
    if (n < NN) {
      if (doRelu) {
#pragma unroll
        for (int o = 0; o < 16; ++o) acc[o] = fmaxf(acc[o], 0.f);
      }
      if (doResid) {
#pragma unroll
        for (int o4 = 0; o4 < 4; ++o4) {
          float4 rv = *(const float4*)&resid[(size_t)n * 64 + q * 16 + o4 * 4];
          acc[o4 * 4 + 0] += rv.x; acc[o4 * 4 + 1] += rv.y;
          acc[o4 * 4 + 2] += rv.z; acc[o4 * 4 + 3] += rv.w;
        }
      }
#pragma unroll
      for (int o4 = 0; o4 < 4; ++o4) {
        float4 r;
        r.x = acc[o4 * 4 + 0]; r.y = acc[o4 * 4 + 1];
        r.z = acc[o4 * 4 + 2]; r.w = acc[o4 * 4 + 3];
        *(float4*)&out[(size_t)n * 64 + q * 16 + o4 * 4] = r;
      }
      if (outh) {
        uint4 u;
        u.x = f2h(acc[0], acc[1]);  u.y = f2h(acc[2], acc[3]);
        u.z = f2h(acc[4], acc[5]);  u.w = f2h(acc[6], acc[7]);
        outh[(size_t)n * 8 + q * 2] = u;
        u.x = f2h(acc[8], acc[9]);  u.y = f2h(acc[10], acc[11]);
        u.z = f2h(acc[12], acc[13]); u.w = f2h(acc[14], acc[15]);
        outh[(size_t)n * 8 + q * 2 + 1] = u;
      }
    }
  }
}

// ---------------- scoring / selection / output ----------------

// scores[n] = tanh((y[n]·wp) / ||wp||)  — invn recomputed per wave (6 shfl)
__global__ __launch_bounds__(256) void score_k(const float* __restrict__ y,
                                               const float* __restrict__ wp,
                                               float* __restrict__ scores) {
  int tid = threadIdx.x;
  int lane = tid & 63, w = tid >> 6;
  int n = blockIdx.x * 4 + w;
  if (n >= NN) return;
  float wv = wp[lane];
  float s = wv * wv;
#pragma unroll
  for (int o = 32; o > 0; o >>= 1) s += __shfl_xor(s, o);
  float invn = 1.0f / sqrtf(s);
  float p = y[(size_t)n * 64 + lane] * wv;
#pragma unroll
  for (int o = 32; o > 0; o >>= 1) p += __shfl_xor(p, o);
  if (lane == 0) scores[n] = tanhf(p * invn);
}

__device__ __forceinline__ bool lexgt(float v1, int i1, float v2, int i2) {
  return (v1 > v2) || (v1 == v2 && i1 < i2);
}

// phase 1: 64 single-wave blocks, each emits its chunk's top-30.
// Per-lane sorted register chain (static indices, fully unrolled) + 30 rounds
// of wave argmax + predicated pop. launch_bounds(64,1) lifts the VGPR cap so
// the 60-reg chain stays in registers (r6's 64-VGPR cap spilled it).
__global__ __launch_bounds__(64, 1) void topk_p1(const float* __restrict__ score,
                                                 float* __restrict__ candv,
                                                 int* __restrict__ candi) {
  int lane = threadIdx.x;
  int base = blockIdx.x * P1CH;
  float lv[TPK]; int li[TPK];
#pragma unroll
  for (int k = 0; k < TPK; ++k) { lv[k] = -3.4e38f; li[k] = 0x7FFFFFFF; }
  for (int k = lane; k < P1CH; k += 64) {
    int idx = base + k;
    if (idx >= NN) break;
    float v = score[idx];
    if (lexgt(v, idx, lv[TPK - 1], li[TPK - 1])) {
      float cv = v; int ci = idx;
#pragma unroll
      for (int m = 0; m < TPK; ++m) {
        bool sw = lexgt(cv, ci, lv[m], li[m]);
        float tv = sw ? lv[m] : cv; int ti = sw ? li[m] : ci;
        lv[m] = sw ? cv : lv[m]; li[m] = sw ? ci : li[m];
        cv = tv; ci = ti;
      }
    }
  }
  for (int r = 0; r < TPK; ++r) {
    float bv = lv[0]; int bi = li[0];
#pragma unroll
    for (int o = 32; o > 0; o >>= 1) {
      float ov = __shfl_xor(bv, o); int oi = __shfl_xor(bi, o);
      if (lexgt(ov, oi, bv, bi)) { bv = ov; bi = oi; }
    }
    if (lane == 0) { candv[blockIdx.x * TPK + r] = bv; candi[blockIdx.x * TPK + r] = bi; }
    bool mine = (li[0] == bi);  // node indices are unique -> exactly one winner
#pragma unroll
    for (int m = 0; m < TPK - 1; ++m) {
      lv[m] = mine ? lv[m + 1] : lv[m];
      li[m] = mine ? li[m + 1] : li[m];
    }
    if (mine) { lv[TPK - 1] = -3.4e38f; li[TPK - 1] = 0x7FFFFFFF; }
  }
}

// phase 2 + final output: single wave merges 64*30 candidates into the global
// top-30, then the same 64 lanes compute out[c] = max_r y[sel_r][c]*val_r.
__global__ __launch_bounds__(64, 1) void topk_p2_final(const float* __restrict__ candv,
                                                       const int* __restrict__ candi,
                                                       const float* __restrict__ y,
                                                       float* __restrict__ out) {
  __shared__ float sV[TPK];
  __shared__ int sI[TPK];
  int lane = threadIdx.x;  // 64
  float lv[TPK]; int li[TPK];
#pragma unroll
  for (int k = 0; k < TPK; ++k) { lv[k] = -3.4e38f; li[k] = 0x7FFFFFFF; }
  for (int k = lane; k < P1B * TPK; k += 64) {
    float v = candv[k]; int id = candi[k];
    if (lexgt(v, id, lv[TPK - 1], li[TPK - 1])) {
      float cv = v; int ci = id;
#pragma unroll
      for (int m = 0; m < TPK; ++m) {
        bool sw = lexgt(cv, ci, lv[m], li[m]);
        float tv = sw ? lv[m] : cv; int ti = sw ? li[m] : ci;
        lv[m] = sw ? cv : lv[m]; li[m] = sw ? ci : li[m];
        cv = tv; ci = ti;
      }
    }
  }
  for (int r = 0; r < TPK; ++r) {
    float bv = lv[0]; int bi = li[0];
#pragma unroll
    for (int o = 32; o > 0; o >>= 1) {
      float ov = __shfl_xor(bv, o); int oi = __shfl_xor(bi, o);
      if (lexgt(ov, oi, bv, bi)) { bv = ov; bi = oi; }
    }
    if (lane == 0) { sV[r] = bv; sI[r] = bi; }
    bool mine = (li[0] == bi);
#pragma unroll
    for (int m = 0; m < TPK - 1; ++m) {
      lv[m] = mine ? lv[m + 1] : lv[m];
      li[m] = mine ? li[m + 1] : li[m];
    }
    if (mine) { lv[TPK - 1] = -3.4e38f; li[TPK - 1] = 0x7FFFFFFF; }
  }
  __syncthreads();
  float m = -3.4e38f;
  for (int r = 0; r < TPK; ++r)
    m = fmaxf(m, y[(size_t)sI[r] * 64 + lane] * sV[r]);
  out[lane] = m;
}

// ---------------- host orchestration ----------------

extern "C" void kernel_launch(void* const* d_in, const int* in_sizes, int n_in,
                              void* d_out, int out_size, void* d_ws, size_t ws_size,
                              hipStream_t stream) {
  const float* x = (const float*)d_in[0];
  const int* ei = (const int*)d_in[1];
  const float* Wl[5] = {(const float*)d_in[2], (const float*)d_in[4], (const float*)d_in[6],
                        (const float*)d_in[8], (const float*)d_in[10]};
  const float* bl[5] = {(const float*)d_in[3], (const float*)d_in[5], (const float*)d_in[7],
                        (const float*)d_in[9], (const float*)d_in[11]};
  const float* Wm = (const float*)d_in[12];
  const float* bm = (const float*)d_in[13];
  const float* wp = (const float*)d_in[14];
  float* out = (float*)d_out;

  uint8_t* base = (uint8_t*)d_ws;
  size_t off = 0;
  auto alloc = [&](size_t bytes) -> void* {
    void* p = base + off;
    off += (bytes + 255) & ~(size_t)255;
    return p;
  };
  int* deg = (int*)alloc(NN * 4);
  int* rowptr = (int*)alloc((NN + 1) * 4);
  int* cursor = (int*)alloc(NN * 4);
  float* dinv = (float*)alloc(NN * 4);
  int* bsum = (int*)alloc(SCNB * 4);
  int* boff = (int*)alloc(SCNB * 4);
  int2* meta = (int2*)alloc((size_t)NNZ * 8);
  float* x0 = (float*)alloc((size_t)NN * 4 * 4);
  float* t4a = (float*)alloc((size_t)NN * 4 * 4);
  float* t4b = (float*)alloc((size_t)NN * 4 * 4);
  float* xcur = (float*)alloc((size_t)NN * 64 * 4);
  float* tA = (float*)alloc((size_t)NN * 64 * 4);
  uint4* xh = (uint4*)alloc((size_t)NN * 64 * 2);   // fp16 x copy
  uint4* thA = (uint4*)alloc((size_t)NN * 64 * 2);  // fp16 state ping
  uint4* thB = (uint4*)alloc((size_t)NN * 64 * 2);  // fp16 state pong
  float* scores = (float*)alloc(NN * 4);
  float* candv = (float*)alloc((size_t)P1B * TPK * 4);
  int* candi = (int*)alloc((size_t)P1B * TPK * 4);

  const int* erow = ei;
  const int* ecol = ei + EE;

  init_deg<<<(NN + 255) / 256, 256, 0, stream>>>(deg);
  count_deg<<<(EE + 255) / 256, 256, 0, stream>>>(ecol, deg);
  scan_bsum<<<SCNB, 256, 0, stream>>>(deg, bsum);
  scan_boff<<<1, 256, 0, stream>>>(bsum, boff);
  scan_write<<<SCNB, 256, 0, stream>>>(deg, boff, rowptr, cursor, dinv);
  scatter_csr<<<(NNZ + 255) / 256, 256, 0, stream>>>(erow, ecol, dinv, cursor, meta);
  extract_x0<<<(NN + 255) / 256, 256, 0, stream>>>(x, (float4*)x0);

  const float AL[5] = {0.7f, 0.7f, 0.35f, 0.7f / 3.0f, 0.175f};

  // layer 0 (cin = 4, f32 — footprint is L2-resident)
  {
    float coef = (1.0f - AL[0]) / (float)KK;
    const float* tin = x0;
    float* tout = t4a;
    for (int k = 1; k <= KK; ++k) {
      float aacc = (k == KK) ? coef : 1.0f;
      float axc = (k == KK) ? AL[0] : 1.0f;
      sweep4<<<(NN + 63) / 64, 256, 0, stream>>>((const float4*)tin, (const float4*)x0,
                                                 (float4*)tout, rowptr, meta, aacc, axc);
      tin = tout;
      tout = (tout == t4a) ? t4b : t4a;
    }
    dense4<<<(NN + 3) / 4, 256, 0, stream>>>(tin, Wl[0], bl[0], xcur, (unsigned int*)xh);
  }
  // layers 1..4 (cin = 64, fp16 propagation state; xh = fp16(xcur) from the
  // previous dense kernel's fused cast)
  for (int l = 1; l < 5; ++l) {
    float coef = (1.0f - AL[l]) / (float)KK;
    const uint4* tin = xh;
    uint4* tout = thA;
    for (int k = 1; k < KK; ++k) {
      sweep64h<<<(NN + 3) / 4, 256, 0, stream>>>(tin, xh, nullptr, tout, nullptr, rowptr, meta,
                                                 1.0f, 1.0f, 0);
      tin = tout;
      tout = (tout == thA) ? thB : thA;
    }
    // final sweep: gather fp16, combine with f32 x, write f32
    sweep64h<<<(NN + 3) / 4, 256, 0, stream>>>(tin, nullptr, (const float4*)xcur, nullptr,
                                               (float4*)tA, rowptr, meta, coef, AL[l], 1);
    dense64<<<(NN + DN - 1) / DN, 256, 0, stream>>>(tA, Wl[l], bl[l], xcur, xcur,
                                                    (l < 4) ? xh : nullptr, 1, (l >= 2) ? 1 : 0);
  }
  // final projection y = x @ Wm.T + bm  -> tA
  dense64<<<(NN + DN - 1) / DN, 256, 0, stream>>>(xcur, Wm, bm, nullptr, tA, nullptr, 0, 0);
  score_k<<<(NN + 3) / 4, 256, 0, stream>>>(tA, wp, scores);
  topk_p1<<<P1B, 64, 0, stream>>>(scores, candv, candi);
  topk_p2_final<<<1, 64, 0, stream>>>(candv, candi, tA, out);
}